// Round 1
// baseline (561.855 us; speedup 1.0000x reference)
//
#include <hip/hip_runtime.h>

#define N_NODES 100000
#define N_EDGES 20000
#define N_PAIRS 640000
#define CH 128      // HEADS * OUT_CH
#define HEADS 4

// ---- workspace layout (bytes) ----
#define OFF_X0    0UL           // 12,800,000 f32 = 51,200,000 B
#define OFF_XE    51200000UL    //  2,560,000 f32 = 10,240,000 B
#define OFF_ALPHA 61440000UL    //     80,000 f32 =    320,000 B
#define OFF_OFFE  61760000UL    //     20,000 i32
#define OFF_CURE  61840000UL    //     20,000 i32
#define OFF_OFFV  61920000UL    //    100,000 i32
#define OFF_CURV  62320000UL    //    100,000 i32
#define OFF_PIDXE 62720000UL    //    640,000 i32
#define OFF_PIDXV 65280000UL    //    640,000 i32
#define OFF_CNTE  67840000UL    //     20,000 i32   } contiguous zero region
#define OFF_CNTV  67920000UL    //    100,000 i32   }
#define OFF_TOT   68320000UL    //          2 i32   }
#define ZERO_BYTES 480008UL     // cnt_e + cnt_v + totals

// ---------------- GEMM: X0 = X @ W  (fp32, X tiled in LDS) ----------------
__global__ __launch_bounds__(256) void k_gemm(const float* __restrict__ X,
                                              const float* __restrict__ W,
                                              float* __restrict__ X0) {
    __shared__ float Xs[64 * CH];
    const int t = threadIdx.x;
    const int base = blockIdx.x * 64;
    const int rows = min(64, N_NODES - base);

    for (int i = t; i < rows * 32; i += 256) {
        int r = i >> 5, c4 = (i & 31) << 2;
        *(float4*)&Xs[r * CH + c4] = *(const float4*)&X[(size_t)(base + r) * CH + c4];
    }
    __syncthreads();

    const int c4 = (t & 31) << 2;   // channel quad
    const int rg = t >> 5;          // row group 0..7 (8 rows each)
    float4 acc[8];
#pragma unroll
    for (int i = 0; i < 8; ++i) acc[i] = make_float4(0.f, 0.f, 0.f, 0.f);

    for (int k = 0; k < CH; ++k) {
        const float4 wv = *(const float4*)&W[k * CH + c4];
#pragma unroll
        for (int i = 0; i < 8; ++i) {
            float xv = Xs[(rg * 8 + i) * CH + k];
            acc[i].x += xv * wv.x; acc[i].y += xv * wv.y;
            acc[i].z += xv * wv.z; acc[i].w += xv * wv.w;
        }
    }
#pragma unroll
    for (int i = 0; i < 8; ++i) {
        int r = rg * 8 + i;
        if (r < rows) *(float4*)&X0[(size_t)(base + r) * CH + c4] = acc[i];
    }
}

// ---------------- histogram of pair counts ----------------
__global__ __launch_bounds__(256) void k_hist(const int* __restrict__ vertex,
                                              const int* __restrict__ edges,
                                              int* __restrict__ cnt_e,
                                              int* __restrict__ cnt_v) {
    int m = blockIdx.x * 256 + threadIdx.x;
    if (m < N_PAIRS) {
        atomicAdd(&cnt_e[edges[m]], 1);
        atomicAdd(&cnt_v[vertex[m]], 1);
    }
}

// ------------- offsets: block-scan + 1 atomic per block -------------
__global__ __launch_bounds__(256) void k_offsets(const int* __restrict__ cnt,
                                                 int* __restrict__ off,
                                                 int* __restrict__ cur,
                                                 int* __restrict__ total,
                                                 int n) {
    __shared__ int s[256];
    __shared__ int base;
    const int t = threadIdx.x;
    const int i = blockIdx.x * 256 + t;
    const int c = (i < n) ? cnt[i] : 0;
    s[t] = c;
    __syncthreads();
    for (int d = 1; d < 256; d <<= 1) {
        int x = (t >= d) ? s[t - d] : 0;
        __syncthreads();
        s[t] += x;
        __syncthreads();
    }
    if (t == 0) base = atomicAdd(total, s[255]);
    __syncthreads();
    if (i < n) {
        int o = base + s[t] - c;   // exclusive
        off[i] = o;
        cur[i] = o;
    }
}

// ---------------- fill CSR pair-index lists ----------------
__global__ __launch_bounds__(256) void k_fill(const int* __restrict__ vertex,
                                              const int* __restrict__ edges,
                                              int* __restrict__ cur_e,
                                              int* __restrict__ cur_v,
                                              int* __restrict__ pidx_e,
                                              int* __restrict__ pidx_v) {
    int m = blockIdx.x * 256 + threadIdx.x;
    if (m < N_PAIRS) {
        int e = edges[m];
        int p = atomicAdd(&cur_e[e], 1);
        pidx_e[p] = m;
        int v = vertex[m];
        int q = atomicAdd(&cur_v[v], 1);
        pidx_v[q] = m;
    }
}

// --------- per-edge: Xe mean + alpha_e = lrelu((Xe*att).sum(-1)) ---------
__global__ __launch_bounds__(128) void k_edge(const float* __restrict__ X0,
                                              const int* __restrict__ vertex,
                                              const int* __restrict__ off_e,
                                              const int* __restrict__ end_e,
                                              const int* __restrict__ pidx,
                                              const float* __restrict__ att,
                                              float* __restrict__ Xe,
                                              float* __restrict__ alpha_le) {
    const int e = blockIdx.x, t = threadIdx.x;
    const int s = off_e[e], en = end_e[e];
    float acc = 0.f;
    for (int j = s; j < en; ++j) {
        int m = pidx[j];
        int v = vertex[m];
        acc += X0[(size_t)v * CH + t];
    }
    const float xe = acc / fmaxf((float)(en - s), 1.0f);
    Xe[(size_t)e * CH + t] = xe;

    float p = xe * att[t];
#pragma unroll
    for (int o = 16; o; o >>= 1) p += __shfl_xor(p, o);
    if ((t & 31) == 0) {
        float a = p;
        alpha_le[e * HEADS + (t >> 5)] = (a > 0.f) ? a : 0.01f * a;
    }
}

// --------- per-vertex: softmax over incident pairs + weighted sum + X0 ---------
__global__ __launch_bounds__(128) void k_vertex(const float* __restrict__ X0,
                                                const float* __restrict__ Xe,
                                                const float* __restrict__ alpha_le,
                                                const int* __restrict__ edges,
                                                const int* __restrict__ off_v,
                                                const int* __restrict__ end_v,
                                                const int* __restrict__ pidx,
                                                float* __restrict__ out) {
    const int v = blockIdx.x, t = threadIdx.x, h = t >> 5;
    const int s = off_v[v], en = end_v[v];

    float mx = -INFINITY;
    for (int j = s; j < en; ++j) {
        int e = edges[pidx[j]];
        mx = fmaxf(mx, alpha_le[e * HEADS + h]);
    }
    float ssum = 0.f;
    for (int j = s; j < en; ++j) {
        int e = edges[pidx[j]];
        ssum += __expf(alpha_le[e * HEADS + h] - mx);
    }
    const float inv = 1.0f / (ssum + 1e-8f);
    float acc = 0.f;
    for (int j = s; j < en; ++j) {
        int e = edges[pidx[j]];
        float w = __expf(alpha_le[e * HEADS + h] - mx) * inv;
        acc += w * Xe[(size_t)e * CH + t];
    }
    out[(size_t)v * CH + t] = acc + X0[(size_t)v * CH + t];
}

extern "C" void kernel_launch(void* const* d_in, const int* in_sizes, int n_in,
                              void* d_out, int out_size, void* d_ws, size_t ws_size,
                              hipStream_t stream) {
    const float* X      = (const float*)d_in[0];
    const float* W      = (const float*)d_in[1];
    const float* att    = (const float*)d_in[2];
    const int*   vertex = (const int*)d_in[3];
    const int*   edges  = (const int*)d_in[4];
    float* out = (float*)d_out;

    char* ws = (char*)d_ws;
    float* X0       = (float*)(ws + OFF_X0);
    float* Xe       = (float*)(ws + OFF_XE);
    float* alpha_le = (float*)(ws + OFF_ALPHA);
    int* off_e  = (int*)(ws + OFF_OFFE);
    int* cur_e  = (int*)(ws + OFF_CURE);
    int* off_v  = (int*)(ws + OFF_OFFV);
    int* cur_v  = (int*)(ws + OFF_CURV);
    int* pidx_e = (int*)(ws + OFF_PIDXE);
    int* pidx_v = (int*)(ws + OFF_PIDXV);
    int* cnt_e  = (int*)(ws + OFF_CNTE);
    int* cnt_v  = (int*)(ws + OFF_CNTV);
    int* totals = (int*)(ws + OFF_TOT);

    // zero the counters (poisoned 0xAA once; must re-zero every call)
    hipMemsetAsync(ws + OFF_CNTE, 0, ZERO_BYTES, stream);

    k_gemm<<<(N_NODES + 63) / 64, 256, 0, stream>>>(X, W, X0);
    k_hist<<<N_PAIRS / 256, 256, 0, stream>>>(vertex, edges, cnt_e, cnt_v);
    k_offsets<<<(N_EDGES + 255) / 256, 256, 0, stream>>>(cnt_e, off_e, cur_e, &totals[0], N_EDGES);
    k_offsets<<<(N_NODES + 255) / 256, 256, 0, stream>>>(cnt_v, off_v, cur_v, &totals[1], N_NODES);
    k_fill<<<N_PAIRS / 256, 256, 0, stream>>>(vertex, edges, cur_e, cur_v, pidx_e, pidx_v);
    // after k_fill, cur_* hold segment END offsets
    k_edge<<<N_EDGES, 128, 0, stream>>>(X0, vertex, off_e, cur_e, pidx_e, att, Xe, alpha_le);
    k_vertex<<<N_NODES, 128, 0, stream>>>(X0, Xe, alpha_le, edges, off_v, cur_v, pidx_v, out);
}

// Round 2
// 363.298 us; speedup vs baseline: 1.5465x; 1.5465x over previous
//
#include <hip/hip_runtime.h>

#define N_NODES 100000
#define N_EDGES 20000
#define N_PAIRS 640000
#define CH 128      // HEADS * OUT_CH
#define HEADS 4
#define MAXD 128    // fast-path segment capacity (Poisson(6.4)/(32) => max ~30/~65)

// ---- workspace layout (bytes) ----
#define OFF_X0    0UL           // 12,800,000 f32 = 51,200,000 B
#define OFF_XE    51200000UL    //  2,560,000 f32 = 10,240,000 B
#define OFF_ALPHA 61440000UL    //     80,000 f32 =    320,000 B
#define OFF_OFFE  61760000UL    //     20,000 i32
#define OFF_CURE  61840000UL    //     20,000 i32
#define OFF_OFFV  61920000UL    //    100,000 i32
#define OFF_CURV  62320000UL    //    100,000 i32
#define OFF_PIDXE 62720000UL    //    640,000 i32 (stores VERTEX ids, edge-grouped)
#define OFF_PIDXV 65280000UL    //    640,000 i32 (stores EDGE ids, vertex-grouped)
#define OFF_CNTE  67840000UL    //     20,000 i32   } contiguous zero region
#define OFF_CNTV  67920000UL    //    100,000 i32   }
#define OFF_TOT   68320000UL    //          2 i32   }
#define ZERO_BYTES 480008UL     // cnt_e + cnt_v + totals

// ---------------- GEMM: X0 = X @ W  (fp32, X tiled in LDS) ----------------
__global__ __launch_bounds__(256) void k_gemm(const float* __restrict__ X,
                                              const float* __restrict__ W,
                                              float* __restrict__ X0) {
    __shared__ float Xs[64 * CH];
    const int t = threadIdx.x;
    const int base = blockIdx.x * 64;
    const int rows = min(64, N_NODES - base);

    for (int i = t; i < rows * 32; i += 256) {
        int r = i >> 5, c4 = (i & 31) << 2;
        *(float4*)&Xs[r * CH + c4] = *(const float4*)&X[(size_t)(base + r) * CH + c4];
    }
    __syncthreads();

    const int c4 = (t & 31) << 2;   // channel quad
    const int rg = t >> 5;          // row group 0..7 (8 rows each)
    float4 acc[8];
#pragma unroll
    for (int i = 0; i < 8; ++i) acc[i] = make_float4(0.f, 0.f, 0.f, 0.f);

    for (int k = 0; k < CH; ++k) {
        const float4 wv = *(const float4*)&W[k * CH + c4];
#pragma unroll
        for (int i = 0; i < 8; ++i) {
            float xv = Xs[(rg * 8 + i) * CH + k];
            acc[i].x += xv * wv.x; acc[i].y += xv * wv.y;
            acc[i].z += xv * wv.z; acc[i].w += xv * wv.w;
        }
    }
#pragma unroll
    for (int i = 0; i < 8; ++i) {
        int r = rg * 8 + i;
        if (r < rows) *(float4*)&X0[(size_t)(base + r) * CH + c4] = acc[i];
    }
}

// ---------------- histogram of pair counts ----------------
__global__ __launch_bounds__(256) void k_hist(const int* __restrict__ vertex,
                                              const int* __restrict__ edges,
                                              int* __restrict__ cnt_e,
                                              int* __restrict__ cnt_v) {
    int m = blockIdx.x * 256 + threadIdx.x;
    if (m < N_PAIRS) {
        atomicAdd(&cnt_e[edges[m]], 1);
        atomicAdd(&cnt_v[vertex[m]], 1);
    }
}

// ------------- offsets: block-scan + 1 atomic per block -------------
__global__ __launch_bounds__(256) void k_offsets(const int* __restrict__ cnt,
                                                 int* __restrict__ off,
                                                 int* __restrict__ cur,
                                                 int* __restrict__ total,
                                                 int n) {
    __shared__ int s[256];
    __shared__ int base;
    const int t = threadIdx.x;
    const int i = blockIdx.x * 256 + t;
    const int c = (i < n) ? cnt[i] : 0;
    s[t] = c;
    __syncthreads();
    for (int d = 1; d < 256; d <<= 1) {
        int x = (t >= d) ? s[t - d] : 0;
        __syncthreads();
        s[t] += x;
        __syncthreads();
    }
    if (t == 0) base = atomicAdd(total, s[255]);
    __syncthreads();
    if (i < n) {
        int o = base + s[t] - c;   // exclusive
        off[i] = o;
        cur[i] = o;
    }
}

// ------- fill CSR lists with direct VALUES (no pair index indirection) -------
__global__ __launch_bounds__(256) void k_fill(const int* __restrict__ vertex,
                                              const int* __restrict__ edges,
                                              int* __restrict__ cur_e,
                                              int* __restrict__ cur_v,
                                              int* __restrict__ vlist_e,
                                              int* __restrict__ elist_v) {
    int m = blockIdx.x * 256 + threadIdx.x;
    if (m < N_PAIRS) {
        int e = edges[m];
        int v = vertex[m];
        int p = atomicAdd(&cur_e[e], 1);
        vlist_e[p] = v;                    // vertex id, grouped by edge
        int q = atomicAdd(&cur_v[v], 1);
        elist_v[q] = e;                    // edge id, grouped by vertex
    }
}

// --------- per-edge: Xe mean + alpha_e = lrelu((Xe*att).sum(-1)) ---------
__global__ __launch_bounds__(128) void k_edge(const float* __restrict__ X0,
                                              const int* __restrict__ off_e,
                                              const int* __restrict__ end_e,
                                              const int* __restrict__ vlist,
                                              const float* __restrict__ att,
                                              float* __restrict__ Xe,
                                              float* __restrict__ alpha_le) {
    const int e = blockIdx.x, t = threadIdx.x;
    const int s = off_e[e], en = end_e[e];
    const int deg = en - s;
    __shared__ int sv[MAXD];

    float acc = 0.f;
    for (int c0 = 0; c0 < deg; c0 += MAXD) {
        const int cn = min(MAXD, deg - c0);
        if (t < cn) sv[t] = vlist[s + c0 + t];
        __syncthreads();
        for (int j = 0; j < cn; ++j)
            acc += X0[(size_t)sv[j] * CH + t];
        __syncthreads();
    }
    const float xe = acc / fmaxf((float)deg, 1.0f);
    Xe[(size_t)e * CH + t] = xe;

    float p = xe * att[t];
#pragma unroll
    for (int o = 16; o; o >>= 1) p += __shfl_xor(p, o);
    if ((t & 31) == 0) {
        float a = p;
        alpha_le[e * HEADS + (t >> 5)] = (a > 0.f) ? a : 0.01f * a;
    }
}

// --------- per-vertex: softmax over incident edges + weighted sum + X0 ---------
__global__ __launch_bounds__(128) void k_vertex(const float* __restrict__ X0,
                                                const float* __restrict__ Xe,
                                                const float* __restrict__ alpha_le,
                                                const int* __restrict__ off_v,
                                                const int* __restrict__ end_v,
                                                const int* __restrict__ elist,
                                                float* __restrict__ out) {
    const int v = blockIdx.x, t = threadIdx.x, h = t >> 5;
    const int s = off_v[v], en = end_v[v];
    const int deg = en - s;
    __shared__ int se[MAXD];
    __shared__ float sa[MAXD * HEADS];

    const float res = X0[(size_t)v * CH + t];   // issue early, overlaps staging

    if (deg <= MAXD) {
        if (t < deg) {
            int e = elist[s + t];
            se[t] = e;
            float4 a = *(const float4*)&alpha_le[e * HEADS];
            sa[t * 4 + 0] = a.x; sa[t * 4 + 1] = a.y;
            sa[t * 4 + 2] = a.z; sa[t * 4 + 3] = a.w;
        }
        __syncthreads();
        float mx = -INFINITY;
        for (int j = 0; j < deg; ++j) mx = fmaxf(mx, sa[j * 4 + h]);
        float ssum = 0.f;
        for (int j = 0; j < deg; ++j) ssum += __expf(sa[j * 4 + h] - mx);
        const float inv = 1.0f / (ssum + 1e-8f);
        float acc = 0.f;
        for (int j = 0; j < deg; ++j) {
            float w = __expf(sa[j * 4 + h] - mx) * inv;
            acc += w * Xe[(size_t)se[j] * CH + t];
        }
        out[(size_t)v * CH + t] = acc + res;
        return;
    }

    // ---- chunked fallback (deg > MAXD; correctness-only path) ----
    float mx = -INFINITY, ssum = 0.f, acc = 0.f;
    for (int pass = 0; pass < 3; ++pass) {
        const float inv = (pass == 2) ? 1.0f / (ssum + 1e-8f) : 0.f;
        for (int c0 = 0; c0 < deg; c0 += MAXD) {
            const int cn = min(MAXD, deg - c0);
            if (t < cn) {
                int e = elist[s + c0 + t];
                se[t] = e;
                float4 a = *(const float4*)&alpha_le[e * HEADS];
                sa[t * 4 + 0] = a.x; sa[t * 4 + 1] = a.y;
                sa[t * 4 + 2] = a.z; sa[t * 4 + 3] = a.w;
            }
            __syncthreads();
            for (int j = 0; j < cn; ++j) {
                float a = sa[j * 4 + h];
                if (pass == 0) mx = fmaxf(mx, a);
                else if (pass == 1) ssum += __expf(a - mx);
                else acc += __expf(a - mx) * inv * Xe[(size_t)se[j] * CH + t];
            }
            __syncthreads();
        }
    }
    out[(size_t)v * CH + t] = acc + res;
}

extern "C" void kernel_launch(void* const* d_in, const int* in_sizes, int n_in,
                              void* d_out, int out_size, void* d_ws, size_t ws_size,
                              hipStream_t stream) {
    const float* X      = (const float*)d_in[0];
    const float* W      = (const float*)d_in[1];
    const float* att    = (const float*)d_in[2];
    const int*   vertex = (const int*)d_in[3];
    const int*   edges  = (const int*)d_in[4];
    float* out = (float*)d_out;

    char* ws = (char*)d_ws;
    float* X0       = (float*)(ws + OFF_X0);
    float* Xe       = (float*)(ws + OFF_XE);
    float* alpha_le = (float*)(ws + OFF_ALPHA);
    int* off_e   = (int*)(ws + OFF_OFFE);
    int* cur_e   = (int*)(ws + OFF_CURE);
    int* off_v   = (int*)(ws + OFF_OFFV);
    int* cur_v   = (int*)(ws + OFF_CURV);
    int* vlist_e = (int*)(ws + OFF_PIDXE);
    int* elist_v = (int*)(ws + OFF_PIDXV);
    int* cnt_e   = (int*)(ws + OFF_CNTE);
    int* cnt_v   = (int*)(ws + OFF_CNTV);
    int* totals  = (int*)(ws + OFF_TOT);

    // zero the counters (poisoned 0xAA once; must re-zero every call)
    hipMemsetAsync(ws + OFF_CNTE, 0, ZERO_BYTES, stream);

    k_gemm<<<(N_NODES + 63) / 64, 256, 0, stream>>>(X, W, X0);
    k_hist<<<N_PAIRS / 256, 256, 0, stream>>>(vertex, edges, cnt_e, cnt_v);
    k_offsets<<<(N_EDGES + 255) / 256, 256, 0, stream>>>(cnt_e, off_e, cur_e, &totals[0], N_EDGES);
    k_offsets<<<(N_NODES + 255) / 256, 256, 0, stream>>>(cnt_v, off_v, cur_v, &totals[1], N_NODES);
    k_fill<<<N_PAIRS / 256, 256, 0, stream>>>(vertex, edges, cur_e, cur_v, vlist_e, elist_v);
    // after k_fill, cur_* hold segment END offsets
    k_edge<<<N_EDGES, 128, 0, stream>>>(X0, off_e, cur_e, vlist_e, att, Xe, alpha_le);
    k_vertex<<<N_NODES, 128, 0, stream>>>(X0, Xe, alpha_le, off_v, cur_v, elist_v, out);
}

// Round 3
// 334.119 us; speedup vs baseline: 1.6816x; 1.0873x over previous
//
#include <hip/hip_runtime.h>

#define N_NODES 100000
#define N_EDGES 20000
#define N_PAIRS 640000
#define CH 128      // HEADS * OUT_CH
#define HEADS 4
#define MAXDV 32    // k_vertex fast-path capacity (Poisson(6.4): max ~25)

// ---- workspace layout (bytes) ----
#define OFF_X0    0UL           // 12,800,000 f32 = 51,200,000 B
#define OFF_XE    51200000UL    //  2,560,000 f32 = 10,240,000 B
#define OFF_ALPHA 61440000UL    //     80,000 f32 =    320,000 B (16B aligned)
#define OFF_OFFE  61760000UL    //     20,000 i32
#define OFF_CURE  61840000UL    //     20,000 i32
#define OFF_OFFV  61920000UL    //    100,000 i32
#define OFF_CURV  62320000UL    //    100,000 i32
#define OFF_PIDXE 62720000UL    //    640,000 i32 (VERTEX ids, edge-grouped)
#define OFF_PIDXV 65280000UL    //    640,000 i32 (EDGE ids, vertex-grouped)
#define OFF_CNTE  67840000UL    //     20,000 i32   } contiguous zero region
#define OFF_CNTV  67920000UL    //    100,000 i32   }
#define OFF_TOT   68320000UL    //          2 i32   }
#define ZERO_BYTES 480008UL

// ---------------- GEMM: X0 = X @ W  (fp32, X tiled in LDS) ----------------
__global__ __launch_bounds__(256) void k_gemm(const float* __restrict__ X,
                                              const float* __restrict__ W,
                                              float* __restrict__ X0) {
    __shared__ float Xs[64 * CH];
    const int t = threadIdx.x;
    const int base = blockIdx.x * 64;
    const int rows = min(64, N_NODES - base);

    for (int i = t; i < rows * 32; i += 256) {
        int r = i >> 5, c4 = (i & 31) << 2;
        *(float4*)&Xs[r * CH + c4] = *(const float4*)&X[(size_t)(base + r) * CH + c4];
    }
    __syncthreads();

    const int c4 = (t & 31) << 2;
    const int rg = t >> 5;
    float4 acc[8];
#pragma unroll
    for (int i = 0; i < 8; ++i) acc[i] = make_float4(0.f, 0.f, 0.f, 0.f);

    for (int k = 0; k < CH; ++k) {
        const float4 wv = *(const float4*)&W[k * CH + c4];
#pragma unroll
        for (int i = 0; i < 8; ++i) {
            float xv = Xs[(rg * 8 + i) * CH + k];
            acc[i].x += xv * wv.x; acc[i].y += xv * wv.y;
            acc[i].z += xv * wv.z; acc[i].w += xv * wv.w;
        }
    }
#pragma unroll
    for (int i = 0; i < 8; ++i) {
        int r = rg * 8 + i;
        if (r < rows) *(float4*)&X0[(size_t)(base + r) * CH + c4] = acc[i];
    }
}

// ---------------- histogram of pair counts ----------------
__global__ __launch_bounds__(256) void k_hist(const int* __restrict__ vertex,
                                              const int* __restrict__ edges,
                                              int* __restrict__ cnt_e,
                                              int* __restrict__ cnt_v) {
    int m = blockIdx.x * 256 + threadIdx.x;
    if (m < N_PAIRS) {
        atomicAdd(&cnt_e[edges[m]], 1);
        atomicAdd(&cnt_v[vertex[m]], 1);
    }
}

// ------------- offsets: block-scan + 1 atomic per block -------------
__global__ __launch_bounds__(256) void k_offsets(const int* __restrict__ cnt,
                                                 int* __restrict__ off,
                                                 int* __restrict__ cur,
                                                 int* __restrict__ total,
                                                 int n) {
    __shared__ int s[256];
    __shared__ int base;
    const int t = threadIdx.x;
    const int i = blockIdx.x * 256 + t;
    const int c = (i < n) ? cnt[i] : 0;
    s[t] = c;
    __syncthreads();
    for (int d = 1; d < 256; d <<= 1) {
        int x = (t >= d) ? s[t - d] : 0;
        __syncthreads();
        s[t] += x;
        __syncthreads();
    }
    if (t == 0) base = atomicAdd(total, s[255]);
    __syncthreads();
    if (i < n) {
        int o = base + s[t] - c;
        off[i] = o;
        cur[i] = o;
    }
}

// ------- fill CSR lists with direct VALUES -------
__global__ __launch_bounds__(256) void k_fill(const int* __restrict__ vertex,
                                              const int* __restrict__ edges,
                                              int* __restrict__ cur_e,
                                              int* __restrict__ cur_v,
                                              int* __restrict__ vlist_e,
                                              int* __restrict__ elist_v) {
    int m = blockIdx.x * 256 + threadIdx.x;
    if (m < N_PAIRS) {
        int e = edges[m];
        int v = vertex[m];
        int p = atomicAdd(&cur_e[e], 1);
        vlist_e[p] = v;
        int q = atomicAdd(&cur_v[v], 1);
        elist_v[q] = e;
    }
}

// --------- per-edge: 32 lanes x float4; ids broadcast via shfl (no LDS) ---------
__global__ __launch_bounds__(256) void k_edge(const float* __restrict__ X0,
                                              const int* __restrict__ off_e,
                                              const int* __restrict__ end_e,
                                              const int* __restrict__ vlist,
                                              const float* __restrict__ att,
                                              float* __restrict__ Xe,
                                              float* __restrict__ alpha_le) {
    const int t = threadIdx.x;
    const int slot = t >> 5, lane = t & 31, h = lane >> 3;
    const int e = blockIdx.x * 8 + slot;           // grid is exactly 20000/8
    const int s = off_e[e], en = end_e[e];
    const int deg = en - s;
    const float4* __restrict__ X04 = (const float4*)X0;

    float4 acc = make_float4(0.f, 0.f, 0.f, 0.f);
    for (int c0 = 0; c0 < deg; c0 += 32) {
        const int cn = min(32, deg - c0);
        int vl = (lane < cn) ? vlist[s + c0 + lane] : 0;
#pragma unroll 4
        for (int j = 0; j < cn; ++j) {
            int vj = __shfl(vl, j, 32);
            float4 x = X04[(size_t)vj * 32 + lane];
            acc.x += x.x; acc.y += x.y; acc.z += x.z; acc.w += x.w;
        }
    }
    const float invd = 1.0f / fmaxf((float)deg, 1.0f);
    float4 xe = make_float4(acc.x * invd, acc.y * invd, acc.z * invd, acc.w * invd);
    ((float4*)Xe)[(size_t)e * 32 + lane] = xe;

    const float4 av = *(const float4*)&att[lane << 2];
    float p = xe.x * av.x + xe.y * av.y + xe.z * av.z + xe.w * av.w;
#pragma unroll
    for (int o = 4; o; o >>= 1) p += __shfl_xor(p, o);   // reduce within 8-lane head group
    if ((lane & 7) == 0) {
        float a = p;
        alpha_le[e * HEADS + h] = (a > 0.f) ? a : 0.01f * a;
    }
}

// --------- per-vertex: 32 lanes x float4; softmax + weighted sum + residual ---------
__global__ __launch_bounds__(256) void k_vertex(const float* __restrict__ X0,
                                                const float* __restrict__ Xe,
                                                const float* __restrict__ alpha_le,
                                                const int* __restrict__ off_v,
                                                const int* __restrict__ end_v,
                                                const int* __restrict__ elist,
                                                float* __restrict__ out) {
    const int t = threadIdx.x;
    const int slot = t >> 5, lane = t & 31, h = lane >> 3;
    const int v = blockIdx.x * 8 + slot;           // grid is exactly 100000/8
    const int s = off_v[v], en = end_v[v];
    const int deg = en - s;
    const float4* __restrict__ X04 = (const float4*)X0;
    const float4* __restrict__ Xe4 = (const float4*)Xe;

    __shared__ int   se[8][MAXDV];
    __shared__ float sa[8][MAXDV * HEADS];

    if (deg <= MAXDV && lane < deg) {
        int e = elist[s + lane];
        se[slot][lane] = e;
        *(float4*)&sa[slot][lane << 2] = *(const float4*)&alpha_le[e * HEADS];
    }
    const float4 res = X04[(size_t)v * 32 + lane];   // overlaps staging
    __syncthreads();

    float4 acc = make_float4(0.f, 0.f, 0.f, 0.f);
    if (deg <= MAXDV) {
        float mx = -INFINITY;
        for (int j = 0; j < deg; ++j) mx = fmaxf(mx, sa[slot][(j << 2) + h]);
        float ssum = 0.f;
        for (int j = 0; j < deg; ++j) ssum += __expf(sa[slot][(j << 2) + h] - mx);
        const float inv = 1.0f / (ssum + 1e-8f);
        for (int j = 0; j < deg; ++j) {
            float w = __expf(sa[slot][(j << 2) + h] - mx) * inv;
            float4 x = Xe4[(size_t)se[slot][j] * 32 + lane];
            acc.x += w * x.x; acc.y += w * x.y; acc.z += w * x.z; acc.w += w * x.w;
        }
    } else {
        // global-memory fallback (never taken for Poisson(6.4); correctness only)
        float mx = -INFINITY;
        for (int j = 0; j < deg; ++j) mx = fmaxf(mx, alpha_le[elist[s + j] * HEADS + h]);
        float ssum = 0.f;
        for (int j = 0; j < deg; ++j) ssum += __expf(alpha_le[elist[s + j] * HEADS + h] - mx);
        const float inv = 1.0f / (ssum + 1e-8f);
        for (int j = 0; j < deg; ++j) {
            int e = elist[s + j];
            float w = __expf(alpha_le[e * HEADS + h] - mx) * inv;
            float4 x = Xe4[(size_t)e * 32 + lane];
            acc.x += w * x.x; acc.y += w * x.y; acc.z += w * x.z; acc.w += w * x.w;
        }
    }
    float4 o = make_float4(acc.x + res.x, acc.y + res.y, acc.z + res.z, acc.w + res.w);
    ((float4*)out)[(size_t)v * 32 + lane] = o;
}

extern "C" void kernel_launch(void* const* d_in, const int* in_sizes, int n_in,
                              void* d_out, int out_size, void* d_ws, size_t ws_size,
                              hipStream_t stream) {
    const float* X      = (const float*)d_in[0];
    const float* W      = (const float*)d_in[1];
    const float* att    = (const float*)d_in[2];
    const int*   vertex = (const int*)d_in[3];
    const int*   edges  = (const int*)d_in[4];
    float* out = (float*)d_out;

    char* ws = (char*)d_ws;
    float* X0       = (float*)(ws + OFF_X0);
    float* Xe       = (float*)(ws + OFF_XE);
    float* alpha_le = (float*)(ws + OFF_ALPHA);
    int* off_e   = (int*)(ws + OFF_OFFE);
    int* cur_e   = (int*)(ws + OFF_CURE);
    int* off_v   = (int*)(ws + OFF_OFFV);
    int* cur_v   = (int*)(ws + OFF_CURV);
    int* vlist_e = (int*)(ws + OFF_PIDXE);
    int* elist_v = (int*)(ws + OFF_PIDXV);
    int* cnt_e   = (int*)(ws + OFF_CNTE);
    int* cnt_v   = (int*)(ws + OFF_CNTV);
    int* totals  = (int*)(ws + OFF_TOT);

    hipMemsetAsync(ws + OFF_CNTE, 0, ZERO_BYTES, stream);

    k_gemm<<<(N_NODES + 63) / 64, 256, 0, stream>>>(X, W, X0);
    k_hist<<<N_PAIRS / 256, 256, 0, stream>>>(vertex, edges, cnt_e, cnt_v);
    k_offsets<<<(N_EDGES + 255) / 256, 256, 0, stream>>>(cnt_e, off_e, cur_e, &totals[0], N_EDGES);
    k_offsets<<<(N_NODES + 255) / 256, 256, 0, stream>>>(cnt_v, off_v, cur_v, &totals[1], N_NODES);
    k_fill<<<N_PAIRS / 256, 256, 0, stream>>>(vertex, edges, cur_e, cur_v, vlist_e, elist_v);
    // after k_fill, cur_* hold segment END offsets
    k_edge<<<N_EDGES / 8, 256, 0, stream>>>(X0, off_e, cur_e, vlist_e, att, Xe, alpha_le);
    k_vertex<<<N_NODES / 8, 256, 0, stream>>>(X0, Xe, alpha_le, off_v, cur_v, elist_v, out);
}

// Round 4
// 255.489 us; speedup vs baseline: 2.1991x; 1.3078x over previous
//
#include <hip/hip_runtime.h>

#define N_NODES 100000
#define N_EDGES 20000
#define N_PAIRS 640000
#define CH 128      // HEADS * OUT_CH
#define HEADS 4
#define MAXDV 32    // k_vertex fast-path capacity (Poisson(6.4): max ~25)

// ---- workspace layout (bytes) ----
#define OFF_X0    0UL           // 12,800,000 f32 = 51,200,000 B
#define OFF_XE    51200000UL    //  2,560,000 f32 = 10,240,000 B  (rank_pack aliases this until k_edge)
#define OFF_ALPHA 61440000UL    //     80,000 f32 =    320,000 B
#define OFF_OFFE  61760000UL    //     20,000 i32
#define OFF_ENDE  61840000UL    //     20,000 i32
#define OFF_OFFV  61920000UL    //    100,000 i32
#define OFF_ENDV  62320000UL    //    100,000 i32
#define OFF_PIDXE 62720000UL    //    640,000 i32 (VERTEX ids, edge-grouped)
#define OFF_PIDXV 65280000UL    //    640,000 i32 (EDGE ids, vertex-grouped)
#define OFF_CNTE  67840000UL    //     20,000 i32   } contiguous zero region
#define OFF_CNTV  67920000UL    //    100,000 i32   }
#define OFF_TOT   68320000UL    //          2 i32   }
#define ZERO_BYTES 480008UL

// ---------------- GEMM: X0 = X @ W  (fp32, X tiled in LDS) ----------------
__global__ __launch_bounds__(256) void k_gemm(const float* __restrict__ X,
                                              const float* __restrict__ W,
                                              float* __restrict__ X0) {
    __shared__ float Xs[64 * CH];
    const int t = threadIdx.x;
    const int base = blockIdx.x * 64;
    const int rows = min(64, N_NODES - base);

    for (int i = t; i < rows * 32; i += 256) {
        int r = i >> 5, c4 = (i & 31) << 2;
        *(float4*)&Xs[r * CH + c4] = *(const float4*)&X[(size_t)(base + r) * CH + c4];
    }
    __syncthreads();

    const int c4 = (t & 31) << 2;
    const int rg = t >> 5;
    float4 acc[8];
#pragma unroll
    for (int i = 0; i < 8; ++i) acc[i] = make_float4(0.f, 0.f, 0.f, 0.f);

    for (int k = 0; k < CH; ++k) {
        const float4 wv = *(const float4*)&W[k * CH + c4];
#pragma unroll
        for (int i = 0; i < 8; ++i) {
            float xv = Xs[(rg * 8 + i) * CH + k];
            acc[i].x += xv * wv.x; acc[i].y += xv * wv.y;
            acc[i].z += xv * wv.z; acc[i].w += xv * wv.w;
        }
    }
#pragma unroll
    for (int i = 0; i < 8; ++i) {
        int r = rg * 8 + i;
        if (r < rows) *(float4*)&X0[(size_t)(base + r) * CH + c4] = acc[i];
    }
}

// ----- rank assignment: one returning atomic per (pair, side); coalesced store -----
// 4 pairs per thread -> 8 independent atomic chains in flight.
__global__ __launch_bounds__(256) void k_rank(const int* __restrict__ vertex,
                                              const int* __restrict__ edges,
                                              int* __restrict__ cnt_e,
                                              int* __restrict__ cnt_v,
                                              unsigned int* __restrict__ rank_pack) {
    const int m0 = (blockIdx.x * 256 + threadIdx.x) * 4;
    const int4 ev = *(const int4*)&edges[m0];
    const int4 vv = *(const int4*)&vertex[m0];
    int re0 = atomicAdd(&cnt_e[ev.x], 1);
    int re1 = atomicAdd(&cnt_e[ev.y], 1);
    int re2 = atomicAdd(&cnt_e[ev.z], 1);
    int re3 = atomicAdd(&cnt_e[ev.w], 1);
    int rv0 = atomicAdd(&cnt_v[vv.x], 1);
    int rv1 = atomicAdd(&cnt_v[vv.y], 1);
    int rv2 = atomicAdd(&cnt_v[vv.z], 1);
    int rv3 = atomicAdd(&cnt_v[vv.w], 1);
    uint4 rp;
    rp.x = (unsigned)(rv0 << 16) | (unsigned)re0;
    rp.y = (unsigned)(rv1 << 16) | (unsigned)re1;
    rp.z = (unsigned)(rv2 << 16) | (unsigned)re2;
    rp.w = (unsigned)(rv3 << 16) | (unsigned)re3;
    *(uint4*)&rank_pack[m0] = rp;
}

// ------------- offsets: block-scan + 1 atomic per block; also writes end -------------
__global__ __launch_bounds__(256) void k_offsets(const int* __restrict__ cnt,
                                                 int* __restrict__ off,
                                                 int* __restrict__ end,
                                                 int* __restrict__ total,
                                                 int n) {
    __shared__ int s[256];
    __shared__ int base;
    const int t = threadIdx.x;
    const int i = blockIdx.x * 256 + t;
    const int c = (i < n) ? cnt[i] : 0;
    s[t] = c;
    __syncthreads();
    for (int d = 1; d < 256; d <<= 1) {
        int x = (t >= d) ? s[t - d] : 0;
        __syncthreads();
        s[t] += x;
        __syncthreads();
    }
    if (t == 0) base = atomicAdd(total, s[255]);
    __syncthreads();
    if (i < n) {
        int o = base + s[t] - c;
        off[i] = o;
        end[i] = o + c;
    }
}

// ------- atomic-free scatter: slot = off[bin] + rank -------
__global__ __launch_bounds__(256) void k_scatter(const int* __restrict__ vertex,
                                                 const int* __restrict__ edges,
                                                 const unsigned int* __restrict__ rank_pack,
                                                 const int* __restrict__ off_e,
                                                 const int* __restrict__ off_v,
                                                 int* __restrict__ vlist_e,
                                                 int* __restrict__ elist_v) {
    const int m0 = (blockIdx.x * 256 + threadIdx.x) * 4;
    const int4 ev = *(const int4*)&edges[m0];
    const int4 vv = *(const int4*)&vertex[m0];
    const uint4 rp = *(const uint4*)&rank_pack[m0];
    // edge-grouped vertex list
    vlist_e[off_e[ev.x] + (int)(rp.x & 0xffffu)] = vv.x;
    vlist_e[off_e[ev.y] + (int)(rp.y & 0xffffu)] = vv.y;
    vlist_e[off_e[ev.z] + (int)(rp.z & 0xffffu)] = vv.z;
    vlist_e[off_e[ev.w] + (int)(rp.w & 0xffffu)] = vv.w;
    // vertex-grouped edge list
    elist_v[off_v[vv.x] + (int)(rp.x >> 16)] = ev.x;
    elist_v[off_v[vv.y] + (int)(rp.y >> 16)] = ev.y;
    elist_v[off_v[vv.z] + (int)(rp.z >> 16)] = ev.z;
    elist_v[off_v[vv.w] + (int)(rp.w >> 16)] = ev.w;
}

// --------- per-edge: 32 lanes x float4; ids broadcast via shfl (no LDS) ---------
__global__ __launch_bounds__(256) void k_edge(const float* __restrict__ X0,
                                              const int* __restrict__ off_e,
                                              const int* __restrict__ end_e,
                                              const int* __restrict__ vlist,
                                              const float* __restrict__ att,
                                              float* __restrict__ Xe,
                                              float* __restrict__ alpha_le) {
    const int t = threadIdx.x;
    const int slot = t >> 5, lane = t & 31, h = lane >> 3;
    const int e = blockIdx.x * 8 + slot;           // grid is exactly 20000/8
    const int s = off_e[e], en = end_e[e];
    const int deg = en - s;
    const float4* __restrict__ X04 = (const float4*)X0;

    float4 acc = make_float4(0.f, 0.f, 0.f, 0.f);
    for (int c0 = 0; c0 < deg; c0 += 32) {
        const int cn = min(32, deg - c0);
        int vl = (lane < cn) ? vlist[s + c0 + lane] : 0;
#pragma unroll 4
        for (int j = 0; j < cn; ++j) {
            int vj = __shfl(vl, j, 32);
            float4 x = X04[(size_t)vj * 32 + lane];
            acc.x += x.x; acc.y += x.y; acc.z += x.z; acc.w += x.w;
        }
    }
    const float invd = 1.0f / fmaxf((float)deg, 1.0f);
    float4 xe = make_float4(acc.x * invd, acc.y * invd, acc.z * invd, acc.w * invd);
    ((float4*)Xe)[(size_t)e * 32 + lane] = xe;

    const float4 av = *(const float4*)&att[lane << 2];
    float p = xe.x * av.x + xe.y * av.y + xe.z * av.z + xe.w * av.w;
#pragma unroll
    for (int o = 4; o; o >>= 1) p += __shfl_xor(p, o);   // reduce within 8-lane head group
    if ((lane & 7) == 0) {
        float a = p;
        alpha_le[e * HEADS + h] = (a > 0.f) ? a : 0.01f * a;
    }
}

// --------- per-vertex: 32 lanes x float4; softmax + weighted sum + residual ---------
__global__ __launch_bounds__(256) void k_vertex(const float* __restrict__ X0,
                                                const float* __restrict__ Xe,
                                                const float* __restrict__ alpha_le,
                                                const int* __restrict__ off_v,
                                                const int* __restrict__ end_v,
                                                const int* __restrict__ elist,
                                                float* __restrict__ out) {
    const int t = threadIdx.x;
    const int slot = t >> 5, lane = t & 31, h = lane >> 3;
    const int v = blockIdx.x * 8 + slot;           // grid is exactly 100000/8
    const int s = off_v[v], en = end_v[v];
    const int deg = en - s;
    const float4* __restrict__ X04 = (const float4*)X0;
    const float4* __restrict__ Xe4 = (const float4*)Xe;

    __shared__ int   se[8][MAXDV];
    __shared__ float sa[8][MAXDV * HEADS];

    if (deg <= MAXDV && lane < deg) {
        int e = elist[s + lane];
        se[slot][lane] = e;
        *(float4*)&sa[slot][lane << 2] = *(const float4*)&alpha_le[e * HEADS];
    }
    const float4 res = X04[(size_t)v * 32 + lane];   // overlaps staging
    __syncthreads();

    float4 acc = make_float4(0.f, 0.f, 0.f, 0.f);
    if (deg <= MAXDV) {
        float mx = -INFINITY;
        for (int j = 0; j < deg; ++j) mx = fmaxf(mx, sa[slot][(j << 2) + h]);
        float ssum = 0.f;
        for (int j = 0; j < deg; ++j) ssum += __expf(sa[slot][(j << 2) + h] - mx);
        const float inv = 1.0f / (ssum + 1e-8f);
        for (int j = 0; j < deg; ++j) {
            float w = __expf(sa[slot][(j << 2) + h] - mx) * inv;
            float4 x = Xe4[(size_t)se[slot][j] * 32 + lane];
            acc.x += w * x.x; acc.y += w * x.y; acc.z += w * x.z; acc.w += w * x.w;
        }
    } else {
        // global-memory fallback (never taken for Poisson(6.4); correctness only)
        float mx = -INFINITY;
        for (int j = 0; j < deg; ++j) mx = fmaxf(mx, alpha_le[elist[s + j] * HEADS + h]);
        float ssum = 0.f;
        for (int j = 0; j < deg; ++j) ssum += __expf(alpha_le[elist[s + j] * HEADS + h] - mx);
        const float inv = 1.0f / (ssum + 1e-8f);
        for (int j = 0; j < deg; ++j) {
            int e = elist[s + j];
            float w = __expf(alpha_le[e * HEADS + h] - mx) * inv;
            float4 x = Xe4[(size_t)e * 32 + lane];
            acc.x += w * x.x; acc.y += w * x.y; acc.z += w * x.z; acc.w += w * x.w;
        }
    }
    float4 o = make_float4(acc.x + res.x, acc.y + res.y, acc.z + res.z, acc.w + res.w);
    ((float4*)out)[(size_t)v * 32 + lane] = o;
}

extern "C" void kernel_launch(void* const* d_in, const int* in_sizes, int n_in,
                              void* d_out, int out_size, void* d_ws, size_t ws_size,
                              hipStream_t stream) {
    const float* X      = (const float*)d_in[0];
    const float* W      = (const float*)d_in[1];
    const float* att    = (const float*)d_in[2];
    const int*   vertex = (const int*)d_in[3];
    const int*   edges  = (const int*)d_in[4];
    float* out = (float*)d_out;

    char* ws = (char*)d_ws;
    float* X0       = (float*)(ws + OFF_X0);
    float* Xe       = (float*)(ws + OFF_XE);
    unsigned int* rank_pack = (unsigned int*)(ws + OFF_XE);   // aliases Xe; dead before k_edge
    float* alpha_le = (float*)(ws + OFF_ALPHA);
    int* off_e   = (int*)(ws + OFF_OFFE);
    int* end_e   = (int*)(ws + OFF_ENDE);
    int* off_v   = (int*)(ws + OFF_OFFV);
    int* end_v   = (int*)(ws + OFF_ENDV);
    int* vlist_e = (int*)(ws + OFF_PIDXE);
    int* elist_v = (int*)(ws + OFF_PIDXV);
    int* cnt_e   = (int*)(ws + OFF_CNTE);
    int* cnt_v   = (int*)(ws + OFF_CNTV);
    int* totals  = (int*)(ws + OFF_TOT);

    hipMemsetAsync(ws + OFF_CNTE, 0, ZERO_BYTES, stream);

    k_gemm<<<(N_NODES + 63) / 64, 256, 0, stream>>>(X, W, X0);
    k_rank<<<N_PAIRS / 1024, 256, 0, stream>>>(vertex, edges, cnt_e, cnt_v, rank_pack);
    k_offsets<<<(N_EDGES + 255) / 256, 256, 0, stream>>>(cnt_e, off_e, end_e, &totals[0], N_EDGES);
    k_offsets<<<(N_NODES + 255) / 256, 256, 0, stream>>>(cnt_v, off_v, end_v, &totals[1], N_NODES);
    k_scatter<<<N_PAIRS / 1024, 256, 0, stream>>>(vertex, edges, rank_pack, off_e, off_v, vlist_e, elist_v);
    k_edge<<<N_EDGES / 8, 256, 0, stream>>>(X0, off_e, end_e, vlist_e, att, Xe, alpha_le);
    k_vertex<<<N_NODES / 8, 256, 0, stream>>>(X0, Xe, alpha_le, off_v, end_v, elist_v, out);
}

// Round 5
// 237.223 us; speedup vs baseline: 2.3685x; 1.0770x over previous
//
#include <hip/hip_runtime.h>
#include <hip/hip_bf16.h>

#define N_NODES 100000
#define N_EDGES 20000
#define N_PAIRS 640000
#define CH 128      // HEADS * OUT_CH
#define HEADS 4
#define MAXDV 32    // k_vertex fast-path capacity (Poisson(6.4): max ~25)

// ---- workspace layout (bytes) ----
#define OFF_X0    0UL           // 12,800,000 f32 = 51,200,000 B
#define OFF_XE    51200000UL    //  2,560,000 f32 = 10,240,000 B (rank_pack + Wt alias here pre-k_edge)
#define OFF_WT    53760000UL    //  16,384 bf16 = 32,768 B (after rank_pack, dead before k_edge)
#define OFF_ALPHA 61440000UL    //     80,000 f32
#define OFF_OFFE  61760000UL
#define OFF_ENDE  61840000UL
#define OFF_OFFV  61920000UL
#define OFF_ENDV  62320000UL
#define OFF_PIDXE 62720000UL    //    640,000 i32 (VERTEX ids, edge-grouped)
#define OFF_PIDXV 65280000UL    //    640,000 i32 (EDGE ids, vertex-grouped)
#define OFF_CNTE  67840000UL    //     20,000 i32   } contiguous zero region
#define OFF_CNTV  67920000UL    //    100,000 i32   }
#define OFF_TOT   68320000UL    //          2 i32   }
#define ZERO_BYTES 480008UL

typedef __attribute__((ext_vector_type(8))) short bf16x8;
typedef __attribute__((ext_vector_type(4))) float f32x4;

__device__ inline short f2bf(float f) {
    __hip_bfloat16 h = __float2bfloat16(f);   // RNE
    return reinterpret_cast<short&>(h);
}

// ---- W prep: Wt[n][k] = bf16(W[k][n])  (B^T layout -> contiguous-k fragments) ----
__global__ __launch_bounds__(256) void k_wprep(const float* __restrict__ W,
                                               short* __restrict__ Wt) {
    const int idx = blockIdx.x * 256 + threadIdx.x;   // grid 64 * 256 = 16384
    const int n = idx >> 7, k = idx & 127;
    Wt[n * CH + k] = f2bf(W[k * CH + n]);
}

// ---------------- GEMM: X0 = X @ W via bf16 MFMA ----------------
// block: 64 rows x 128 cols, 4 waves (2M x 2N), wave tile 32x64.
__global__ __launch_bounds__(256) void k_gemm(const float* __restrict__ X,
                                              const short* __restrict__ Wt,
                                              float* __restrict__ X0) {
    const int t = threadIdx.x;
    const int wave = t >> 6, lane = t & 63;
    const int r0 = blockIdx.x * 64 + (wave >> 1) * 32;   // wave row base
    const int c0 = (wave & 1) * 64;                      // wave col base
    const int lrow = lane & 15, lk8 = (lane >> 4) * 8;

    f32x4 acc[2][4] = {};

#pragma unroll
    for (int kk = 0; kk < 4; ++kk) {
        const int ks = kk * 32 + lk8;
        bf16x8 a[2], b[4];
#pragma unroll
        for (int m = 0; m < 2; ++m) {
            int row = r0 + m * 16 + lrow;
            row = min(row, N_NODES - 1);               // tail clamp (garbage rows masked at store)
            const float* p = &X[(size_t)row * CH + ks];
            const float4 x0 = *(const float4*)p;
            const float4 x1 = *(const float4*)(p + 4);
            a[m][0] = f2bf(x0.x); a[m][1] = f2bf(x0.y);
            a[m][2] = f2bf(x0.z); a[m][3] = f2bf(x0.w);
            a[m][4] = f2bf(x1.x); a[m][5] = f2bf(x1.y);
            a[m][6] = f2bf(x1.z); a[m][7] = f2bf(x1.w);
        }
#pragma unroll
        for (int n = 0; n < 4; ++n) {
            int col = c0 + n * 16 + lrow;
            b[n] = *(const bf16x8*)&Wt[col * CH + ks];
        }
#pragma unroll
        for (int m = 0; m < 2; ++m)
#pragma unroll
            for (int n = 0; n < 4; ++n)
                acc[m][n] = __builtin_amdgcn_mfma_f32_16x16x32_bf16(a[m], b[n], acc[m][n], 0, 0, 0);
    }

    // C/D layout: col = lane&15, row = (lane>>4)*4 + reg   [m89-verified]
#pragma unroll
    for (int m = 0; m < 2; ++m) {
#pragma unroll
        for (int reg = 0; reg < 4; ++reg) {
            const int row = r0 + m * 16 + (lane >> 4) * 4 + reg;
            if (row < N_NODES) {
#pragma unroll
                for (int n = 0; n < 4; ++n)
                    X0[(size_t)row * CH + c0 + n * 16 + (lane & 15)] = acc[m][n][reg];
            }
        }
    }
}

// ----- rank assignment: one returning atomic per (pair, side); coalesced store -----
__global__ __launch_bounds__(256) void k_rank(const int* __restrict__ vertex,
                                              const int* __restrict__ edges,
                                              int* __restrict__ cnt_e,
                                              int* __restrict__ cnt_v,
                                              unsigned int* __restrict__ rank_pack) {
    const int m0 = (blockIdx.x * 256 + threadIdx.x) * 4;
    const int4 ev = *(const int4*)&edges[m0];
    const int4 vv = *(const int4*)&vertex[m0];
    int re0 = atomicAdd(&cnt_e[ev.x], 1);
    int re1 = atomicAdd(&cnt_e[ev.y], 1);
    int re2 = atomicAdd(&cnt_e[ev.z], 1);
    int re3 = atomicAdd(&cnt_e[ev.w], 1);
    int rv0 = atomicAdd(&cnt_v[vv.x], 1);
    int rv1 = atomicAdd(&cnt_v[vv.y], 1);
    int rv2 = atomicAdd(&cnt_v[vv.z], 1);
    int rv3 = atomicAdd(&cnt_v[vv.w], 1);
    uint4 rp;
    rp.x = (unsigned)(rv0 << 16) | (unsigned)re0;
    rp.y = (unsigned)(rv1 << 16) | (unsigned)re1;
    rp.z = (unsigned)(rv2 << 16) | (unsigned)re2;
    rp.w = (unsigned)(rv3 << 16) | (unsigned)re3;
    *(uint4*)&rank_pack[m0] = rp;
}

// ------------- offsets: block-scan + 1 atomic per block; also writes end -------------
__global__ __launch_bounds__(256) void k_offsets(const int* __restrict__ cnt,
                                                 int* __restrict__ off,
                                                 int* __restrict__ end,
                                                 int* __restrict__ total,
                                                 int n) {
    __shared__ int s[256];
    __shared__ int base;
    const int t = threadIdx.x;
    const int i = blockIdx.x * 256 + t;
    const int c = (i < n) ? cnt[i] : 0;
    s[t] = c;
    __syncthreads();
    for (int d = 1; d < 256; d <<= 1) {
        int x = (t >= d) ? s[t - d] : 0;
        __syncthreads();
        s[t] += x;
        __syncthreads();
    }
    if (t == 0) base = atomicAdd(total, s[255]);
    __syncthreads();
    if (i < n) {
        int o = base + s[t] - c;
        off[i] = o;
        end[i] = o + c;
    }
}

// ------- atomic-free scatter: slot = off[bin] + rank -------
__global__ __launch_bounds__(256) void k_scatter(const int* __restrict__ vertex,
                                                 const int* __restrict__ edges,
                                                 const unsigned int* __restrict__ rank_pack,
                                                 const int* __restrict__ off_e,
                                                 const int* __restrict__ off_v,
                                                 int* __restrict__ vlist_e,
                                                 int* __restrict__ elist_v) {
    const int m0 = (blockIdx.x * 256 + threadIdx.x) * 4;
    const int4 ev = *(const int4*)&edges[m0];
    const int4 vv = *(const int4*)&vertex[m0];
    const uint4 rp = *(const uint4*)&rank_pack[m0];
    vlist_e[off_e[ev.x] + (int)(rp.x & 0xffffu)] = vv.x;
    vlist_e[off_e[ev.y] + (int)(rp.y & 0xffffu)] = vv.y;
    vlist_e[off_e[ev.z] + (int)(rp.z & 0xffffu)] = vv.z;
    vlist_e[off_e[ev.w] + (int)(rp.w & 0xffffu)] = vv.w;
    elist_v[off_v[vv.x] + (int)(rp.x >> 16)] = ev.x;
    elist_v[off_v[vv.y] + (int)(rp.y >> 16)] = ev.y;
    elist_v[off_v[vv.z] + (int)(rp.z >> 16)] = ev.z;
    elist_v[off_v[vv.w] + (int)(rp.w >> 16)] = ev.w;
}

// --------- per-edge: 32 lanes x float4; ids broadcast via shfl (no LDS) ---------
__global__ __launch_bounds__(256) void k_edge(const float* __restrict__ X0,
                                              const int* __restrict__ off_e,
                                              const int* __restrict__ end_e,
                                              const int* __restrict__ vlist,
                                              const float* __restrict__ att,
                                              float* __restrict__ Xe,
                                              float* __restrict__ alpha_le) {
    const int t = threadIdx.x;
    const int slot = t >> 5, lane = t & 31, h = lane >> 3;
    const int e = blockIdx.x * 8 + slot;
    const int s = off_e[e], en = end_e[e];
    const int deg = en - s;
    const float4* __restrict__ X04 = (const float4*)X0;

    float4 acc = make_float4(0.f, 0.f, 0.f, 0.f);
    for (int c0 = 0; c0 < deg; c0 += 32) {
        const int cn = min(32, deg - c0);
        int vl = (lane < cn) ? vlist[s + c0 + lane] : 0;
#pragma unroll 4
        for (int j = 0; j < cn; ++j) {
            int vj = __shfl(vl, j, 32);
            float4 x = X04[(size_t)vj * 32 + lane];
            acc.x += x.x; acc.y += x.y; acc.z += x.z; acc.w += x.w;
        }
    }
    const float invd = 1.0f / fmaxf((float)deg, 1.0f);
    float4 xe = make_float4(acc.x * invd, acc.y * invd, acc.z * invd, acc.w * invd);
    ((float4*)Xe)[(size_t)e * 32 + lane] = xe;

    const float4 av = *(const float4*)&att[lane << 2];
    float p = xe.x * av.x + xe.y * av.y + xe.z * av.z + xe.w * av.w;
#pragma unroll
    for (int o = 4; o; o >>= 1) p += __shfl_xor(p, o);
    if ((lane & 7) == 0) {
        float a = p;
        alpha_le[e * HEADS + h] = (a > 0.f) ? a : 0.01f * a;
    }
}

// --------- per-vertex: 32 lanes x float4; softmax + weighted sum + residual ---------
__global__ __launch_bounds__(256) void k_vertex(const float* __restrict__ X0,
                                                const float* __restrict__ Xe,
                                                const float* __restrict__ alpha_le,
                                                const int* __restrict__ off_v,
                                                const int* __restrict__ end_v,
                                                const int* __restrict__ elist,
                                                float* __restrict__ out) {
    const int t = threadIdx.x;
    const int slot = t >> 5, lane = t & 31, h = lane >> 3;
    const int v = blockIdx.x * 8 + slot;
    const int s = off_v[v], en = end_v[v];
    const int deg = en - s;
    const float4* __restrict__ X04 = (const float4*)X0;
    const float4* __restrict__ Xe4 = (const float4*)Xe;

    __shared__ int   se[8][MAXDV];
    __shared__ float sa[8][MAXDV * HEADS];

    if (deg <= MAXDV && lane < deg) {
        int e = elist[s + lane];
        se[slot][lane] = e;
        *(float4*)&sa[slot][lane << 2] = *(const float4*)&alpha_le[e * HEADS];
    }
    const float4 res = X04[(size_t)v * 32 + lane];
    __syncthreads();

    float4 acc = make_float4(0.f, 0.f, 0.f, 0.f);
    if (deg <= MAXDV) {
        float mx = -INFINITY;
        for (int j = 0; j < deg; ++j) mx = fmaxf(mx, sa[slot][(j << 2) + h]);
        float ssum = 0.f;
        for (int j = 0; j < deg; ++j) ssum += __expf(sa[slot][(j << 2) + h] - mx);
        const float inv = 1.0f / (ssum + 1e-8f);
        for (int j = 0; j < deg; ++j) {
            float w = __expf(sa[slot][(j << 2) + h] - mx) * inv;
            float4 x = Xe4[(size_t)se[slot][j] * 32 + lane];
            acc.x += w * x.x; acc.y += w * x.y; acc.z += w * x.z; acc.w += w * x.w;
        }
    } else {
        float mx = -INFINITY;
        for (int j = 0; j < deg; ++j) mx = fmaxf(mx, alpha_le[elist[s + j] * HEADS + h]);
        float ssum = 0.f;
        for (int j = 0; j < deg; ++j) ssum += __expf(alpha_le[elist[s + j] * HEADS + h] - mx);
        const float inv = 1.0f / (ssum + 1e-8f);
        for (int j = 0; j < deg; ++j) {
            int e = elist[s + j];
            float w = __expf(alpha_le[e * HEADS + h] - mx) * inv;
            float4 x = Xe4[(size_t)e * 32 + lane];
            acc.x += w * x.x; acc.y += w * x.y; acc.z += w * x.z; acc.w += w * x.w;
        }
    }
    float4 o = make_float4(acc.x + res.x, acc.y + res.y, acc.z + res.z, acc.w + res.w);
    ((float4*)out)[(size_t)v * 32 + lane] = o;
}

extern "C" void kernel_launch(void* const* d_in, const int* in_sizes, int n_in,
                              void* d_out, int out_size, void* d_ws, size_t ws_size,
                              hipStream_t stream) {
    const float* X      = (const float*)d_in[0];
    const float* W      = (const float*)d_in[1];
    const float* att    = (const float*)d_in[2];
    const int*   vertex = (const int*)d_in[3];
    const int*   edges  = (const int*)d_in[4];
    float* out = (float*)d_out;

    char* ws = (char*)d_ws;
    float* X0       = (float*)(ws + OFF_X0);
    float* Xe       = (float*)(ws + OFF_XE);
    unsigned int* rank_pack = (unsigned int*)(ws + OFF_XE);   // aliases Xe; dead before k_edge
    short* Wt       = (short*)(ws + OFF_WT);                  // aliases Xe tail; dead before k_edge
    float* alpha_le = (float*)(ws + OFF_ALPHA);
    int* off_e   = (int*)(ws + OFF_OFFE);
    int* end_e   = (int*)(ws + OFF_ENDE);
    int* off_v   = (int*)(ws + OFF_OFFV);
    int* end_v   = (int*)(ws + OFF_ENDV);
    int* vlist_e = (int*)(ws + OFF_PIDXE);
    int* elist_v = (int*)(ws + OFF_PIDXV);
    int* cnt_e   = (int*)(ws + OFF_CNTE);
    int* cnt_v   = (int*)(ws + OFF_CNTV);
    int* totals  = (int*)(ws + OFF_TOT);

    hipMemsetAsync(ws + OFF_CNTE, 0, ZERO_BYTES, stream);

    k_wprep<<<64, 256, 0, stream>>>(W, Wt);
    k_gemm<<<(N_NODES + 63) / 64, 256, 0, stream>>>(X, Wt, X0);
    k_rank<<<N_PAIRS / 1024, 256, 0, stream>>>(vertex, edges, cnt_e, cnt_v, rank_pack);
    k_offsets<<<(N_EDGES + 255) / 256, 256, 0, stream>>>(cnt_e, off_e, end_e, &totals[0], N_EDGES);
    k_offsets<<<(N_NODES + 255) / 256, 256, 0, stream>>>(cnt_v, off_v, end_v, &totals[1], N_NODES);
    k_scatter<<<N_PAIRS / 1024, 256, 0, stream>>>(vertex, edges, rank_pack, off_e, off_v, vlist_e, elist_v);
    k_edge<<<N_EDGES / 8, 256, 0, stream>>>(X0, off_e, end_e, vlist_e, att, Xe, alpha_le);
    k_vertex<<<N_NODES / 8, 256, 0, stream>>>(X0, Xe, alpha_le, off_v, end_v, elist_v, out);
}

// Round 6
// 201.134 us; speedup vs baseline: 2.7934x; 1.1794x over previous
//
#include <hip/hip_runtime.h>
#include <hip/hip_bf16.h>

#define N_NODES 100000
#define N_EDGES 20000
#define N_PAIRS 640000
#define CH 128      // HEADS * OUT_CH
#define HEADS 4
#define MAXDV 32    // k_vertex fast-path capacity (Poisson(6.4): max ~25)

// ---- workspace layout (bytes), all 16B-aligned ----
#define OFF_X0H   0UL           // 12,800,000 bf16 = 25,600,000 B
#define OFF_XEH   25600000UL    //  2,560,000 bf16 =  5,120,000 B
#define OFF_RANK  30720000UL    //    640,000 u32  =  2,560,000 B
#define OFF_WT    33280000UL    //     16,384 bf16 =     32,768 B
#define OFF_ALPHA 33320000UL    //     80,000 f32  =    320,000 B
#define OFF_OFFE  33640000UL    //     20,000 i32
#define OFF_ENDE  33720000UL    //     20,000 i32
#define OFF_OFFV  33800000UL    //    100,000 i32
#define OFF_ENDV  34200000UL    //    100,000 i32
#define OFF_PIDXE 34600000UL    //    640,000 i32 (VERTEX ids, edge-grouped)
#define OFF_PIDXV 37160000UL    //    640,000 i32 (EDGE ids, vertex-grouped)
#define OFF_CNTE  39720000UL    //     20,000 i32   } contiguous zero region
#define OFF_CNTV  39800000UL    //    100,000 i32   }
#define OFF_TOT   40200000UL    //          2 i32   }
#define ZERO_BYTES 480008UL

typedef __attribute__((ext_vector_type(8))) short bf16x8;
typedef __attribute__((ext_vector_type(4))) float f32x4;

__device__ inline short f2bf(float f) {
    __hip_bfloat16 h = __float2bfloat16(f);   // RNE
    return reinterpret_cast<short&>(h);
}
__device__ inline float bf2f(short s) {
    unsigned int u = ((unsigned int)(unsigned short)s) << 16;
    union { unsigned int u; float f; } c; c.u = u;
    return c.f;
}

// ---- W prep: Wt[n][k] = bf16(W[k][n])  (B^T layout -> contiguous-k fragments) ----
__global__ __launch_bounds__(256) void k_wprep(const float* __restrict__ W,
                                               short* __restrict__ Wt) {
    const int idx = blockIdx.x * 256 + threadIdx.x;   // grid 64 * 256 = 16384
    const int n = idx >> 7, k = idx & 127;
    Wt[n * CH + k] = f2bf(W[k * CH + n]);
}

// ---------------- GEMM: X0h = bf16(X @ W) via bf16 MFMA ----------------
// block: 64 rows x 128 cols, 4 waves (2M x 2N), wave tile 32x64.
__global__ __launch_bounds__(256) void k_gemm(const float* __restrict__ X,
                                              const short* __restrict__ Wt,
                                              short* __restrict__ X0h) {
    const int t = threadIdx.x;
    const int wave = t >> 6, lane = t & 63;
    const int r0 = blockIdx.x * 64 + (wave >> 1) * 32;   // wave row base
    const int c0 = (wave & 1) * 64;                      // wave col base
    const int lrow = lane & 15, lk8 = (lane >> 4) * 8;

    f32x4 acc[2][4] = {};

#pragma unroll
    for (int kk = 0; kk < 4; ++kk) {
        const int ks = kk * 32 + lk8;
        bf16x8 a[2], b[4];
#pragma unroll
        for (int m = 0; m < 2; ++m) {
            int row = r0 + m * 16 + lrow;
            row = min(row, N_NODES - 1);               // tail clamp (masked at store)
            const float* p = &X[(size_t)row * CH + ks];
            const float4 x0 = *(const float4*)p;
            const float4 x1 = *(const float4*)(p + 4);
            a[m][0] = f2bf(x0.x); a[m][1] = f2bf(x0.y);
            a[m][2] = f2bf(x0.z); a[m][3] = f2bf(x0.w);
            a[m][4] = f2bf(x1.x); a[m][5] = f2bf(x1.y);
            a[m][6] = f2bf(x1.z); a[m][7] = f2bf(x1.w);
        }
#pragma unroll
        for (int n = 0; n < 4; ++n) {
            int col = c0 + n * 16 + lrow;
            b[n] = *(const bf16x8*)&Wt[col * CH + ks];
        }
#pragma unroll
        for (int m = 0; m < 2; ++m)
#pragma unroll
            for (int n = 0; n < 4; ++n)
                acc[m][n] = __builtin_amdgcn_mfma_f32_16x16x32_bf16(a[m], b[n], acc[m][n], 0, 0, 0);
    }

    // C/D layout: col = lane&15, row = (lane>>4)*4 + reg   [m89-verified]
#pragma unroll
    for (int m = 0; m < 2; ++m) {
#pragma unroll
        for (int reg = 0; reg < 4; ++reg) {
            const int row = r0 + m * 16 + (lane >> 4) * 4 + reg;
            if (row < N_NODES) {
#pragma unroll
                for (int n = 0; n < 4; ++n)
                    X0h[(size_t)row * CH + c0 + n * 16 + (lane & 15)] = f2bf(acc[m][n][reg]);
            }
        }
    }
}

// ----- rank assignment: one returning atomic per (pair, side); coalesced store -----
__global__ __launch_bounds__(256) void k_rank(const int* __restrict__ vertex,
                                              const int* __restrict__ edges,
                                              int* __restrict__ cnt_e,
                                              int* __restrict__ cnt_v,
                                              unsigned int* __restrict__ rank_pack) {
    const int m0 = (blockIdx.x * 256 + threadIdx.x) * 4;
    const int4 ev = *(const int4*)&edges[m0];
    const int4 vv = *(const int4*)&vertex[m0];
    int re0 = atomicAdd(&cnt_e[ev.x], 1);
    int re1 = atomicAdd(&cnt_e[ev.y], 1);
    int re2 = atomicAdd(&cnt_e[ev.z], 1);
    int re3 = atomicAdd(&cnt_e[ev.w], 1);
    int rv0 = atomicAdd(&cnt_v[vv.x], 1);
    int rv1 = atomicAdd(&cnt_v[vv.y], 1);
    int rv2 = atomicAdd(&cnt_v[vv.z], 1);
    int rv3 = atomicAdd(&cnt_v[vv.w], 1);
    uint4 rp;
    rp.x = (unsigned)(rv0 << 16) | (unsigned)re0;
    rp.y = (unsigned)(rv1 << 16) | (unsigned)re1;
    rp.z = (unsigned)(rv2 << 16) | (unsigned)re2;
    rp.w = (unsigned)(rv3 << 16) | (unsigned)re3;
    *(uint4*)&rank_pack[m0] = rp;
}

// ------------- offsets: block-scan + 1 atomic per block; also writes end -------------
__global__ __launch_bounds__(256) void k_offsets(const int* __restrict__ cnt,
                                                 int* __restrict__ off,
                                                 int* __restrict__ end,
                                                 int* __restrict__ total,
                                                 int n) {
    __shared__ int s[256];
    __shared__ int base;
    const int t = threadIdx.x;
    const int i = blockIdx.x * 256 + t;
    const int c = (i < n) ? cnt[i] : 0;
    s[t] = c;
    __syncthreads();
    for (int d = 1; d < 256; d <<= 1) {
        int x = (t >= d) ? s[t - d] : 0;
        __syncthreads();
        s[t] += x;
        __syncthreads();
    }
    if (t == 0) base = atomicAdd(total, s[255]);
    __syncthreads();
    if (i < n) {
        int o = base + s[t] - c;
        off[i] = o;
        end[i] = o + c;
    }
}

// ------- atomic-free scatter: slot = off[bin] + rank -------
__global__ __launch_bounds__(256) void k_scatter(const int* __restrict__ vertex,
                                                 const int* __restrict__ edges,
                                                 const unsigned int* __restrict__ rank_pack,
                                                 const int* __restrict__ off_e,
                                                 const int* __restrict__ off_v,
                                                 int* __restrict__ vlist_e,
                                                 int* __restrict__ elist_v) {
    const int m0 = (blockIdx.x * 256 + threadIdx.x) * 4;
    const int4 ev = *(const int4*)&edges[m0];
    const int4 vv = *(const int4*)&vertex[m0];
    const uint4 rp = *(const uint4*)&rank_pack[m0];
    vlist_e[off_e[ev.x] + (int)(rp.x & 0xffffu)] = vv.x;
    vlist_e[off_e[ev.y] + (int)(rp.y & 0xffffu)] = vv.y;
    vlist_e[off_e[ev.z] + (int)(rp.z & 0xffffu)] = vv.z;
    vlist_e[off_e[ev.w] + (int)(rp.w & 0xffffu)] = vv.w;
    elist_v[off_v[vv.x] + (int)(rp.x >> 16)] = ev.x;
    elist_v[off_v[vv.y] + (int)(rp.y >> 16)] = ev.y;
    elist_v[off_v[vv.z] + (int)(rp.z >> 16)] = ev.z;
    elist_v[off_v[vv.w] + (int)(rp.w >> 16)] = ev.w;
}

// --------- per-edge: 32 lanes x 4ch; bf16 gathers, f32 accumulate ---------
__global__ __launch_bounds__(256) void k_edge(const short* __restrict__ X0h,
                                              const int* __restrict__ off_e,
                                              const int* __restrict__ end_e,
                                              const int* __restrict__ vlist,
                                              const float* __restrict__ att,
                                              short* __restrict__ Xeh,
                                              float* __restrict__ alpha_le) {
    const int t = threadIdx.x;
    const int slot = t >> 5, lane = t & 31, h = lane >> 3;
    const int e = blockIdx.x * 8 + slot;           // grid is exactly 20000/8
    const int s = off_e[e], en = end_e[e];
    const int deg = en - s;

    float4 acc = make_float4(0.f, 0.f, 0.f, 0.f);
    for (int c0 = 0; c0 < deg; c0 += 32) {
        const int cn = min(32, deg - c0);
        int vl = (lane < cn) ? vlist[s + c0 + lane] : 0;
#pragma unroll 4
        for (int j = 0; j < cn; ++j) {
            int vj = __shfl(vl, j, 32);
            short4 x = *(const short4*)&X0h[(size_t)vj * CH + (lane << 2)];
            acc.x += bf2f(x.x); acc.y += bf2f(x.y);
            acc.z += bf2f(x.z); acc.w += bf2f(x.w);
        }
    }
    const float invd = 1.0f / fmaxf((float)deg, 1.0f);
    float4 xe = make_float4(acc.x * invd, acc.y * invd, acc.z * invd, acc.w * invd);
    short4 xh;
    xh.x = f2bf(xe.x); xh.y = f2bf(xe.y); xh.z = f2bf(xe.z); xh.w = f2bf(xe.w);
    *(short4*)&Xeh[(size_t)e * CH + (lane << 2)] = xh;

    const float4 av = *(const float4*)&att[lane << 2];
    float p = xe.x * av.x + xe.y * av.y + xe.z * av.z + xe.w * av.w;
#pragma unroll
    for (int o = 4; o; o >>= 1) p += __shfl_xor(p, o);   // reduce within 8-lane head group
    if ((lane & 7) == 0) {
        float a = p;
        alpha_le[e * HEADS + h] = (a > 0.f) ? a : 0.01f * a;
    }
}

// --------- per-vertex: bf16 gathers; softmax + weighted sum + residual ---------
__global__ __launch_bounds__(256) void k_vertex(const short* __restrict__ X0h,
                                                const short* __restrict__ Xeh,
                                                const float* __restrict__ alpha_le,
                                                const int* __restrict__ off_v,
                                                const int* __restrict__ end_v,
                                                const int* __restrict__ elist,
                                                float* __restrict__ out) {
    const int t = threadIdx.x;
    const int slot = t >> 5, lane = t & 31, h = lane >> 3;
    const int v = blockIdx.x * 8 + slot;           // grid is exactly 100000/8
    const int s = off_v[v], en = end_v[v];
    const int deg = en - s;

    __shared__ int   se[8][MAXDV];
    __shared__ float sa[8][MAXDV * HEADS];

    if (deg <= MAXDV && lane < deg) {
        int e = elist[s + lane];
        se[slot][lane] = e;
        *(float4*)&sa[slot][lane << 2] = *(const float4*)&alpha_le[e * HEADS];
    }
    const short4 resh = *(const short4*)&X0h[(size_t)v * CH + (lane << 2)];
    __syncthreads();

    float4 acc = make_float4(0.f, 0.f, 0.f, 0.f);
    if (deg <= MAXDV) {
        float mx = -INFINITY;
        for (int j = 0; j < deg; ++j) mx = fmaxf(mx, sa[slot][(j << 2) + h]);
        float ssum = 0.f;
        for (int j = 0; j < deg; ++j) ssum += __expf(sa[slot][(j << 2) + h] - mx);
        const float inv = 1.0f / (ssum + 1e-8f);
        for (int j = 0; j < deg; ++j) {
            float w = __expf(sa[slot][(j << 2) + h] - mx) * inv;
            short4 x = *(const short4*)&Xeh[(size_t)se[slot][j] * CH + (lane << 2)];
            acc.x += w * bf2f(x.x); acc.y += w * bf2f(x.y);
            acc.z += w * bf2f(x.z); acc.w += w * bf2f(x.w);
        }
    } else {
        // global-memory fallback (never taken for Poisson(6.4); correctness only)
        float mx = -INFINITY;
        for (int j = 0; j < deg; ++j) mx = fmaxf(mx, alpha_le[elist[s + j] * HEADS + h]);
        float ssum = 0.f;
        for (int j = 0; j < deg; ++j) ssum += __expf(alpha_le[elist[s + j] * HEADS + h] - mx);
        const float inv = 1.0f / (ssum + 1e-8f);
        for (int j = 0; j < deg; ++j) {
            int e = elist[s + j];
            float w = __expf(alpha_le[e * HEADS + h] - mx) * inv;
            short4 x = *(const short4*)&Xeh[(size_t)e * CH + (lane << 2)];
            acc.x += w * bf2f(x.x); acc.y += w * bf2f(x.y);
            acc.z += w * bf2f(x.z); acc.w += w * bf2f(x.w);
        }
    }
    float4 o = make_float4(acc.x + bf2f(resh.x), acc.y + bf2f(resh.y),
                           acc.z + bf2f(resh.z), acc.w + bf2f(resh.w));
    ((float4*)out)[(size_t)v * 32 + lane] = o;
}

extern "C" void kernel_launch(void* const* d_in, const int* in_sizes, int n_in,
                              void* d_out, int out_size, void* d_ws, size_t ws_size,
                              hipStream_t stream) {
    const float* X      = (const float*)d_in[0];
    const float* W      = (const float*)d_in[1];
    const float* att    = (const float*)d_in[2];
    const int*   vertex = (const int*)d_in[3];
    const int*   edges  = (const int*)d_in[4];
    float* out = (float*)d_out;

    char* ws = (char*)d_ws;
    short* X0h      = (short*)(ws + OFF_X0H);
    short* Xeh      = (short*)(ws + OFF_XEH);
    unsigned int* rank_pack = (unsigned int*)(ws + OFF_RANK);
    short* Wt       = (short*)(ws + OFF_WT);
    float* alpha_le = (float*)(ws + OFF_ALPHA);
    int* off_e   = (int*)(ws + OFF_OFFE);
    int* end_e   = (int*)(ws + OFF_ENDE);
    int* off_v   = (int*)(ws + OFF_OFFV);
    int* end_v   = (int*)(ws + OFF_ENDV);
    int* vlist_e = (int*)(ws + OFF_PIDXE);
    int* elist_v = (int*)(ws + OFF_PIDXV);
    int* cnt_e   = (int*)(ws + OFF_CNTE);
    int* cnt_v   = (int*)(ws + OFF_CNTV);
    int* totals  = (int*)(ws + OFF_TOT);

    hipMemsetAsync(ws + OFF_CNTE, 0, ZERO_BYTES, stream);

    k_wprep<<<64, 256, 0, stream>>>(W, Wt);
    k_gemm<<<(N_NODES + 63) / 64, 256, 0, stream>>>(X, Wt, X0h);
    k_rank<<<N_PAIRS / 1024, 256, 0, stream>>>(vertex, edges, cnt_e, cnt_v, rank_pack);
    k_offsets<<<(N_EDGES + 255) / 256, 256, 0, stream>>>(cnt_e, off_e, end_e, &totals[0], N_EDGES);
    k_offsets<<<(N_NODES + 255) / 256, 256, 0, stream>>>(cnt_v, off_v, end_v, &totals[1], N_NODES);
    k_scatter<<<N_PAIRS / 1024, 256, 0, stream>>>(vertex, edges, rank_pack, off_e, off_v, vlist_e, elist_v);
    k_edge<<<N_EDGES / 8, 256, 0, stream>>>(X0h, off_e, end_e, vlist_e, att, Xeh, alpha_le);
    k_vertex<<<N_NODES / 8, 256, 0, stream>>>(X0h, Xeh, alpha_le, off_v, end_v, elist_v, out);
}

// Round 7
// 201.115 us; speedup vs baseline: 2.7937x; 1.0001x over previous
//
#include <hip/hip_runtime.h>
#include <hip/hip_bf16.h>

#define N_NODES 100000
#define N_EDGES 20000
#define N_PAIRS 640000
#define CH 128      // HEADS * OUT_CH
#define HEADS 4
#define MAXDV 32    // k_vertex fast-path capacity (Poisson(6.4): max ~25)

// ---- workspace layout (bytes), all 16B-aligned ----
#define OFF_X0H   0UL           // 12,800,000 bf16 = 25,600,000 B
#define OFF_XEH   25600000UL    //  2,560,000 bf16 =  5,120,000 B
#define OFF_RANK  30720000UL    //    640,000 u32  =  2,560,000 B
#define OFF_WT    33280000UL    //     16,384 bf16 =     32,768 B
#define OFF_ALPHA 33320000UL    //     80,000 f32  =    320,000 B
#define OFF_OFFE  33640000UL    //     20,000 i32
#define OFF_ENDE  33720000UL    //     20,000 i32
#define OFF_OFFV  33800000UL    //    100,000 i32
#define OFF_ENDV  34200000UL    //    100,000 i32
#define OFF_PIDXE 34600000UL    //    640,000 i32 (VERTEX ids, edge-grouped)
#define OFF_PIDXV 37160000UL    //    640,000 i32 (EDGE ids, vertex-grouped)
#define OFF_CNTE  39720000UL    //     20,000 i32   } contiguous zero region
#define OFF_CNTV  39800000UL    //    100,000 i32   }
#define OFF_TOT   40200000UL    //          2 i32   }
#define ZERO_BYTES 480008UL

typedef __attribute__((ext_vector_type(8))) short bf16x8;
typedef __attribute__((ext_vector_type(4))) float f32x4;

__device__ inline short f2bf(float f) {
    __hip_bfloat16 h = __float2bfloat16(f);   // RNE
    return reinterpret_cast<short&>(h);
}
__device__ inline float bf2f(short s) {
    unsigned int u = ((unsigned int)(unsigned short)s) << 16;
    union { unsigned int u; float f; } c; c.u = u;
    return c.f;
}

// ---- W prep: Wt[n][k] = bf16(W[k][n])  (B^T layout -> contiguous-k fragments) ----
__global__ __launch_bounds__(256) void k_wprep(const float* __restrict__ W,
                                               short* __restrict__ Wt) {
    const int idx = blockIdx.x * 256 + threadIdx.x;   // grid 64 * 256 = 16384
    const int n = idx >> 7, k = idx & 127;
    Wt[n * CH + k] = f2bf(W[k * CH + n]);
}

// ---------------- GEMM: X0h = bf16(X @ W) via bf16 MFMA ----------------
// block: 64 rows x 128 cols, 4 waves (2M x 2N), wave tile 32x64.
__global__ __launch_bounds__(256) void k_gemm(const float* __restrict__ X,
                                              const short* __restrict__ Wt,
                                              short* __restrict__ X0h) {
    const int t = threadIdx.x;
    const int wave = t >> 6, lane = t & 63;
    const int r0 = blockIdx.x * 64 + (wave >> 1) * 32;   // wave row base
    const int c0 = (wave & 1) * 64;                      // wave col base
    const int lrow = lane & 15, lk8 = (lane >> 4) * 8;

    f32x4 acc[2][4] = {};

#pragma unroll
    for (int kk = 0; kk < 4; ++kk) {
        const int ks = kk * 32 + lk8;
        bf16x8 a[2], b[4];
#pragma unroll
        for (int m = 0; m < 2; ++m) {
            int row = r0 + m * 16 + lrow;
            row = min(row, N_NODES - 1);               // tail clamp (masked at store)
            const float* p = &X[(size_t)row * CH + ks];
            const float4 x0 = *(const float4*)p;
            const float4 x1 = *(const float4*)(p + 4);
            a[m][0] = f2bf(x0.x); a[m][1] = f2bf(x0.y);
            a[m][2] = f2bf(x0.z); a[m][3] = f2bf(x0.w);
            a[m][4] = f2bf(x1.x); a[m][5] = f2bf(x1.y);
            a[m][6] = f2bf(x1.z); a[m][7] = f2bf(x1.w);
        }
#pragma unroll
        for (int n = 0; n < 4; ++n) {
            int col = c0 + n * 16 + lrow;
            b[n] = *(const bf16x8*)&Wt[col * CH + ks];
        }
#pragma unroll
        for (int m = 0; m < 2; ++m)
#pragma unroll
            for (int n = 0; n < 4; ++n)
                acc[m][n] = __builtin_amdgcn_mfma_f32_16x16x32_bf16(a[m], b[n], acc[m][n], 0, 0, 0);
    }

    // C/D layout: col = lane&15, row = (lane>>4)*4 + reg   [m89-verified]
#pragma unroll
    for (int m = 0; m < 2; ++m) {
#pragma unroll
        for (int reg = 0; reg < 4; ++reg) {
            const int row = r0 + m * 16 + (lane >> 4) * 4 + reg;
            if (row < N_NODES) {
#pragma unroll
                for (int n = 0; n < 4; ++n)
                    X0h[(size_t)row * CH + c0 + n * 16 + (lane & 15)] = f2bf(acc[m][n][reg]);
            }
        }
    }
}

// ----- rank assignment: 1 pair/thread for max wave-level parallelism -----
__global__ __launch_bounds__(256) void k_rank(const int* __restrict__ vertex,
                                              const int* __restrict__ edges,
                                              int* __restrict__ cnt_e,
                                              int* __restrict__ cnt_v,
                                              unsigned int* __restrict__ rank_pack) {
    const int m = blockIdx.x * 256 + threadIdx.x;
    const int e = edges[m];
    const int v = vertex[m];
    int re = atomicAdd(&cnt_e[e], 1);
    int rv = atomicAdd(&cnt_v[v], 1);
    rank_pack[m] = ((unsigned)rv << 16) | (unsigned)re;
}

// ------------- offsets: block-scan + 1 atomic per block; also writes end -------------
__global__ __launch_bounds__(256) void k_offsets(const int* __restrict__ cnt,
                                                 int* __restrict__ off,
                                                 int* __restrict__ end,
                                                 int* __restrict__ total,
                                                 int n) {
    __shared__ int s[256];
    __shared__ int base;
    const int t = threadIdx.x;
    const int i = blockIdx.x * 256 + t;
    const int c = (i < n) ? cnt[i] : 0;
    s[t] = c;
    __syncthreads();
    for (int d = 1; d < 256; d <<= 1) {
        int x = (t >= d) ? s[t - d] : 0;
        __syncthreads();
        s[t] += x;
        __syncthreads();
    }
    if (t == 0) base = atomicAdd(total, s[255]);
    __syncthreads();
    if (i < n) {
        int o = base + s[t] - c;
        off[i] = o;
        end[i] = o + c;
    }
}

// ------- atomic-free scatter: 1 pair/thread; slot = off[bin] + rank -------
__global__ __launch_bounds__(256) void k_scatter(const int* __restrict__ vertex,
                                                 const int* __restrict__ edges,
                                                 const unsigned int* __restrict__ rank_pack,
                                                 const int* __restrict__ off_e,
                                                 const int* __restrict__ off_v,
                                                 int* __restrict__ vlist_e,
                                                 int* __restrict__ elist_v) {
    const int m = blockIdx.x * 256 + threadIdx.x;
    const int e = edges[m];
    const int v = vertex[m];
    const unsigned rp = rank_pack[m];
    vlist_e[off_e[e] + (int)(rp & 0xffffu)] = v;
    elist_v[off_v[v] + (int)(rp >> 16)] = e;
}

// --------- per-edge: 32 lanes x 4ch; bf16 gathers, f32 accumulate ---------
__global__ __launch_bounds__(256) void k_edge(const short* __restrict__ X0h,
                                              const int* __restrict__ off_e,
                                              const int* __restrict__ end_e,
                                              const int* __restrict__ vlist,
                                              const float* __restrict__ att,
                                              short* __restrict__ Xeh,
                                              float* __restrict__ alpha_le) {
    const int t = threadIdx.x;
    const int slot = t >> 5, lane = t & 31, h = lane >> 3;
    const int e = blockIdx.x * 8 + slot;           // grid is exactly 20000/8
    const int s = off_e[e], en = end_e[e];
    const int deg = en - s;

    float4 acc = make_float4(0.f, 0.f, 0.f, 0.f);
    for (int c0 = 0; c0 < deg; c0 += 32) {
        const int cn = min(32, deg - c0);
        int vl = (lane < cn) ? vlist[s + c0 + lane] : 0;
#pragma unroll 4
        for (int j = 0; j < cn; ++j) {
            int vj = __shfl(vl, j, 32);
            short4 x = *(const short4*)&X0h[(size_t)vj * CH + (lane << 2)];
            acc.x += bf2f(x.x); acc.y += bf2f(x.y);
            acc.z += bf2f(x.z); acc.w += bf2f(x.w);
        }
    }
    const float invd = 1.0f / fmaxf((float)deg, 1.0f);
    float4 xe = make_float4(acc.x * invd, acc.y * invd, acc.z * invd, acc.w * invd);
    short4 xh;
    xh.x = f2bf(xe.x); xh.y = f2bf(xe.y); xh.z = f2bf(xe.z); xh.w = f2bf(xe.w);
    *(short4*)&Xeh[(size_t)e * CH + (lane << 2)] = xh;

    const float4 av = *(const float4*)&att[lane << 2];
    float p = xe.x * av.x + xe.y * av.y + xe.z * av.z + xe.w * av.w;
#pragma unroll
    for (int o = 4; o; o >>= 1) p += __shfl_xor(p, o);   // reduce within 8-lane head group
    if ((lane & 7) == 0) {
        float a = p;
        alpha_le[e * HEADS + h] = (a > 0.f) ? a : 0.01f * a;
    }
}

// --------- per-vertex: bf16 gathers; softmax + weighted sum + residual ---------
__global__ __launch_bounds__(256) void k_vertex(const short* __restrict__ X0h,
                                                const short* __restrict__ Xeh,
                                                const float* __restrict__ alpha_le,
                                                const int* __restrict__ off_v,
                                                const int* __restrict__ end_v,
                                                const int* __restrict__ elist,
                                                float* __restrict__ out) {
    const int t = threadIdx.x;
    const int slot = t >> 5, lane = t & 31, h = lane >> 3;
    const int v = blockIdx.x * 8 + slot;           // grid is exactly 100000/8
    const int s = off_v[v], en = end_v[v];
    const int deg = en - s;

    __shared__ int   se[8][MAXDV];
    __shared__ float sa[8][MAXDV * HEADS];

    if (deg <= MAXDV && lane < deg) {
        int e = elist[s + lane];
        se[slot][lane] = e;
        *(float4*)&sa[slot][lane << 2] = *(const float4*)&alpha_le[e * HEADS];
    }
    const short4 resh = *(const short4*)&X0h[(size_t)v * CH + (lane << 2)];
    __syncthreads();

    float4 acc = make_float4(0.f, 0.f, 0.f, 0.f);
    if (deg <= MAXDV) {
        float mx = -INFINITY;
        for (int j = 0; j < deg; ++j) mx = fmaxf(mx, sa[slot][(j << 2) + h]);
        float ssum = 0.f;
        for (int j = 0; j < deg; ++j) ssum += __expf(sa[slot][(j << 2) + h] - mx);
        const float inv = 1.0f / (ssum + 1e-8f);
        for (int j = 0; j < deg; ++j) {
            float w = __expf(sa[slot][(j << 2) + h] - mx) * inv;
            short4 x = *(const short4*)&Xeh[(size_t)se[slot][j] * CH + (lane << 2)];
            acc.x += w * bf2f(x.x); acc.y += w * bf2f(x.y);
            acc.z += w * bf2f(x.z); acc.w += w * bf2f(x.w);
        }
    } else {
        // global-memory fallback (never taken for Poisson(6.4); correctness only)
        float mx = -INFINITY;
        for (int j = 0; j < deg; ++j) mx = fmaxf(mx, alpha_le[elist[s + j] * HEADS + h]);
        float ssum = 0.f;
        for (int j = 0; j < deg; ++j) ssum += __expf(alpha_le[elist[s + j] * HEADS + h] - mx);
        const float inv = 1.0f / (ssum + 1e-8f);
        for (int j = 0; j < deg; ++j) {
            int e = elist[s + j];
            float w = __expf(alpha_le[e * HEADS + h] - mx) * inv;
            short4 x = *(const short4*)&Xeh[(size_t)e * CH + (lane << 2)];
            acc.x += w * bf2f(x.x); acc.y += w * bf2f(x.y);
            acc.z += w * bf2f(x.z); acc.w += w * bf2f(x.w);
        }
    }
    float4 o = make_float4(acc.x + bf2f(resh.x), acc.y + bf2f(resh.y),
                           acc.z + bf2f(resh.z), acc.w + bf2f(resh.w));
    ((float4*)out)[(size_t)v * 32 + lane] = o;
}

extern "C" void kernel_launch(void* const* d_in, const int* in_sizes, int n_in,
                              void* d_out, int out_size, void* d_ws, size_t ws_size,
                              hipStream_t stream) {
    const float* X      = (const float*)d_in[0];
    const float* W      = (const float*)d_in[1];
    const float* att    = (const float*)d_in[2];
    const int*   vertex = (const int*)d_in[3];
    const int*   edges  = (const int*)d_in[4];
    float* out = (float*)d_out;

    char* ws = (char*)d_ws;
    short* X0h      = (short*)(ws + OFF_X0H);
    short* Xeh      = (short*)(ws + OFF_XEH);
    unsigned int* rank_pack = (unsigned int*)(ws + OFF_RANK);
    short* Wt       = (short*)(ws + OFF_WT);
    float* alpha_le = (float*)(ws + OFF_ALPHA);
    int* off_e   = (int*)(ws + OFF_OFFE);
    int* end_e   = (int*)(ws + OFF_ENDE);
    int* off_v   = (int*)(ws + OFF_OFFV);
    int* end_v   = (int*)(ws + OFF_ENDV);
    int* vlist_e = (int*)(ws + OFF_PIDXE);
    int* elist_v = (int*)(ws + OFF_PIDXV);
    int* cnt_e   = (int*)(ws + OFF_CNTE);
    int* cnt_v   = (int*)(ws + OFF_CNTV);
    int* totals  = (int*)(ws + OFF_TOT);

    hipMemsetAsync(ws + OFF_CNTE, 0, ZERO_BYTES, stream);

    k_wprep<<<64, 256, 0, stream>>>(W, Wt);
    k_gemm<<<(N_NODES + 63) / 64, 256, 0, stream>>>(X, Wt, X0h);
    k_rank<<<N_PAIRS / 256, 256, 0, stream>>>(vertex, edges, cnt_e, cnt_v, rank_pack);
    k_offsets<<<(N_EDGES + 255) / 256, 256, 0, stream>>>(cnt_e, off_e, end_e, &totals[0], N_EDGES);
    k_offsets<<<(N_NODES + 255) / 256, 256, 0, stream>>>(cnt_v, off_v, end_v, &totals[1], N_NODES);
    k_scatter<<<N_PAIRS / 256, 256, 0, stream>>>(vertex, edges, rank_pack, off_e, off_v, vlist_e, elist_v);
    k_edge<<<N_EDGES / 8, 256, 0, stream>>>(X0h, off_e, end_e, vlist_e, att, Xeh, alpha_le);
    k_vertex<<<N_NODES / 8, 256, 0, stream>>>(X0h, Xeh, alpha_le, off_v, end_v, elist_v, out);
}

// Round 8
// 174.232 us; speedup vs baseline: 3.2248x; 1.1543x over previous
//
#include <hip/hip_runtime.h>
#include <hip/hip_bf16.h>

#define N_NODES 100000
#define N_EDGES 20000
#define N_PAIRS 640000
#define CH 128      // HEADS * OUT_CH
#define HEADS 4
#define MAXDV 32    // k_vertex fast-path capacity (Poisson(6.4): max ~25)

#define NG_GEMM 1563            // (N_NODES+63)/64
#define NR_RANK 2500            // N_PAIRS/256
#define INTERLEAVE (2*NG_GEMM)  // 3126

// ---- workspace layout (bytes), all 16B-aligned ----
#define OFF_X0H   0UL           // 12,800,000 bf16 = 25,600,000 B
#define OFF_XEH   25600000UL    //  2,560,000 bf16 =  5,120,000 B
#define OFF_RANK  30720000UL    //    640,000 u32  =  2,560,000 B
#define OFF_WT    33280000UL    //     16,384 bf16 =     32,768 B
#define OFF_ALPHA 33320000UL    //     80,000 f32  =    320,000 B
#define OFF_OFFE  33640000UL    //     20,000 i32
#define OFF_ENDE  33720000UL    //     20,000 i32
#define OFF_OFFV  33800000UL    //    100,000 i32
#define OFF_ENDV  34200000UL    //    100,000 i32
#define OFF_PIDXE 34600000UL    //    640,000 i32 (VERTEX ids, edge-grouped)
#define OFF_PIDXV 37160000UL    //    640,000 i32 (EDGE ids, vertex-grouped)
#define OFF_CNTE  39720000UL    //     20,000 i32   } contiguous zero region
#define OFF_CNTV  39800000UL    //    100,000 i32   }
#define OFF_TOT   40200000UL    //          2 i32   }
#define ZERO_BYTES 480008UL

typedef __attribute__((ext_vector_type(8))) short bf16x8;
typedef __attribute__((ext_vector_type(4))) float f32x4;

__device__ inline short f2bf(float f) {
    __hip_bfloat16 h = __float2bfloat16(f);   // RNE
    return reinterpret_cast<short&>(h);
}
__device__ inline float bf2f(short s) {
    unsigned int u = ((unsigned int)(unsigned short)s) << 16;
    union { unsigned int u; float f; } c; c.u = u;
    return c.f;
}

// ---- W prep: Wt[n][k] = bf16(W[k][n])  (B^T layout -> contiguous-k fragments) ----
__global__ __launch_bounds__(256) void k_wprep(const float* __restrict__ W,
                                               short* __restrict__ Wt) {
    const int idx = blockIdx.x * 256 + threadIdx.x;   // grid 64 * 256 = 16384
    const int n = idx >> 7, k = idx & 127;
    Wt[n * CH + k] = f2bf(W[k * CH + n]);
}

// ================= FUSED: gemm-role blocks ∥ rank-role blocks =================
// gemm role: X0h = bf16(X @ W), 64 rows x 128 cols per block, 4 waves (2Mx2N).
// rank role: one returning atomic per (pair, side) — pure memory-system work.
// Interleaved block ids keep both populations co-resident so the MFMA/VALU
// pipes run under the device-scope atomic throughput wall.
__device__ inline void gemm_body(int gb, const float* __restrict__ X,
                                 const short* __restrict__ Wt,
                                 short* __restrict__ X0h) {
    const int t = threadIdx.x;
    const int wave = t >> 6, lane = t & 63;
    const int r0 = gb * 64 + (wave >> 1) * 32;           // wave row base
    const int c0 = (wave & 1) * 64;                      // wave col base
    const int lrow = lane & 15, lk8 = (lane >> 4) * 8;

    f32x4 acc[2][4] = {};

#pragma unroll
    for (int kk = 0; kk < 4; ++kk) {
        const int ks = kk * 32 + lk8;
        bf16x8 a[2], b[4];
#pragma unroll
        for (int m = 0; m < 2; ++m) {
            int row = r0 + m * 16 + lrow;
            row = min(row, N_NODES - 1);               // tail clamp (masked at store)
            const float* p = &X[(size_t)row * CH + ks];
            const float4 x0 = *(const float4*)p;
            const float4 x1 = *(const float4*)(p + 4);
            a[m][0] = f2bf(x0.x); a[m][1] = f2bf(x0.y);
            a[m][2] = f2bf(x0.z); a[m][3] = f2bf(x0.w);
            a[m][4] = f2bf(x1.x); a[m][5] = f2bf(x1.y);
            a[m][6] = f2bf(x1.z); a[m][7] = f2bf(x1.w);
        }
#pragma unroll
        for (int n = 0; n < 4; ++n) {
            int col = c0 + n * 16 + lrow;
            b[n] = *(const bf16x8*)&Wt[col * CH + ks];
        }
#pragma unroll
        for (int m = 0; m < 2; ++m)
#pragma unroll
            for (int n = 0; n < 4; ++n)
                acc[m][n] = __builtin_amdgcn_mfma_f32_16x16x32_bf16(a[m], b[n], acc[m][n], 0, 0, 0);
    }

    // C/D layout: col = lane&15, row = (lane>>4)*4 + reg   [m89-verified]
#pragma unroll
    for (int m = 0; m < 2; ++m) {
#pragma unroll
        for (int reg = 0; reg < 4; ++reg) {
            const int row = r0 + m * 16 + (lane >> 4) * 4 + reg;
            if (row < N_NODES) {
#pragma unroll
                for (int n = 0; n < 4; ++n)
                    X0h[(size_t)row * CH + c0 + n * 16 + (lane & 15)] = f2bf(acc[m][n][reg]);
            }
        }
    }
}

__device__ inline void rank_body(int rb, const int* __restrict__ vertex,
                                 const int* __restrict__ edges,
                                 int* __restrict__ cnt_e,
                                 int* __restrict__ cnt_v,
                                 unsigned int* __restrict__ rank_pack) {
    const int m = rb * 256 + threadIdx.x;
    const int e = edges[m];
    const int v = vertex[m];
    int re = atomicAdd(&cnt_e[e], 1);
    int rv = atomicAdd(&cnt_v[v], 1);
    rank_pack[m] = ((unsigned)rv << 16) | (unsigned)re;
}

__global__ __launch_bounds__(256) void k_gemm_rank(const float* __restrict__ X,
                                                   const short* __restrict__ Wt,
                                                   short* __restrict__ X0h,
                                                   const int* __restrict__ vertex,
                                                   const int* __restrict__ edges,
                                                   int* __restrict__ cnt_e,
                                                   int* __restrict__ cnt_v,
                                                   unsigned int* __restrict__ rank_pack) {
    const int bid = blockIdx.x;
    if (bid < INTERLEAVE) {
        if ((bid & 1) == 0) gemm_body(bid >> 1, X, Wt, X0h);
        else                rank_body(bid >> 1, vertex, edges, cnt_e, cnt_v, rank_pack);
    } else {
        rank_body(bid - INTERLEAVE + NG_GEMM, vertex, edges, cnt_e, cnt_v, rank_pack);
    }
}

// ------------- offsets (both sides, role by blockIdx): block-scan + 1 atomic -------------
__global__ __launch_bounds__(256) void k_offsets2(const int* __restrict__ cnt_e,
                                                  int* __restrict__ off_e,
                                                  int* __restrict__ end_e,
                                                  const int* __restrict__ cnt_v,
                                                  int* __restrict__ off_v,
                                                  int* __restrict__ end_v,
                                                  int* __restrict__ totals) {
    __shared__ int s[256];
    __shared__ int base;
    const int bid = blockIdx.x, t = threadIdx.x;
    const int* cnt; int* off; int* end; int* total; int n, i;
    if (bid < 79) { cnt = cnt_e; off = off_e; end = end_e; total = &totals[0]; n = N_EDGES;  i = bid * 256 + t; }
    else          { cnt = cnt_v; off = off_v; end = end_v; total = &totals[1]; n = N_NODES; i = (bid - 79) * 256 + t; }
    const int c = (i < n) ? cnt[i] : 0;
    s[t] = c;
    __syncthreads();
    for (int d = 1; d < 256; d <<= 1) {
        int x = (t >= d) ? s[t - d] : 0;
        __syncthreads();
        s[t] += x;
        __syncthreads();
    }
    if (t == 0) base = atomicAdd(total, s[255]);
    __syncthreads();
    if (i < n) {
        int o = base + s[t] - c;
        off[i] = o;
        end[i] = o + c;
    }
}

// ------- atomic-free scatter: 1 pair/thread; slot = off[bin] + rank -------
__global__ __launch_bounds__(256) void k_scatter(const int* __restrict__ vertex,
                                                 const int* __restrict__ edges,
                                                 const unsigned int* __restrict__ rank_pack,
                                                 const int* __restrict__ off_e,
                                                 const int* __restrict__ off_v,
                                                 int* __restrict__ vlist_e,
                                                 int* __restrict__ elist_v) {
    const int m = blockIdx.x * 256 + threadIdx.x;
    const int e = edges[m];
    const int v = vertex[m];
    const unsigned rp = rank_pack[m];
    vlist_e[off_e[e] + (int)(rp & 0xffffu)] = v;
    elist_v[off_v[v] + (int)(rp >> 16)] = e;
}

// --------- per-edge: 32 lanes x 4ch; bf16 gathers, f32 accumulate ---------
__global__ __launch_bounds__(256) void k_edge(const short* __restrict__ X0h,
                                              const int* __restrict__ off_e,
                                              const int* __restrict__ end_e,
                                              const int* __restrict__ vlist,
                                              const float* __restrict__ att,
                                              short* __restrict__ Xeh,
                                              float* __restrict__ alpha_le) {
    const int t = threadIdx.x;
    const int slot = t >> 5, lane = t & 31, h = lane >> 3;
    const int e = blockIdx.x * 8 + slot;           // grid is exactly 20000/8
    const int s = off_e[e], en = end_e[e];
    const int deg = en - s;

    float4 acc = make_float4(0.f, 0.f, 0.f, 0.f);
    for (int c0 = 0; c0 < deg; c0 += 32) {
        const int cn = min(32, deg - c0);
        int vl = (lane < cn) ? vlist[s + c0 + lane] : 0;
#pragma unroll 4
        for (int j = 0; j < cn; ++j) {
            int vj = __shfl(vl, j, 32);
            short4 x = *(const short4*)&X0h[(size_t)vj * CH + (lane << 2)];
            acc.x += bf2f(x.x); acc.y += bf2f(x.y);
            acc.z += bf2f(x.z); acc.w += bf2f(x.w);
        }
    }
    const float invd = 1.0f / fmaxf((float)deg, 1.0f);
    float4 xe = make_float4(acc.x * invd, acc.y * invd, acc.z * invd, acc.w * invd);
    short4 xh;
    xh.x = f2bf(xe.x); xh.y = f2bf(xe.y); xh.z = f2bf(xe.z); xh.w = f2bf(xe.w);
    *(short4*)&Xeh[(size_t)e * CH + (lane << 2)] = xh;

    const float4 av = *(const float4*)&att[lane << 2];
    float p = xe.x * av.x + xe.y * av.y + xe.z * av.z + xe.w * av.w;
#pragma unroll
    for (int o = 4; o; o >>= 1) p += __shfl_xor(p, o);   // reduce within 8-lane head group
    if ((lane & 7) == 0) {
        float a = p;
        alpha_le[e * HEADS + h] = (a > 0.f) ? a : 0.01f * a;
    }
}

// --------- per-vertex: bf16 gathers; softmax + weighted sum + residual ---------
__global__ __launch_bounds__(256) void k_vertex(const short* __restrict__ X0h,
                                                const short* __restrict__ Xeh,
                                                const float* __restrict__ alpha_le,
                                                const int* __restrict__ off_v,
                                                const int* __restrict__ end_v,
                                                const int* __restrict__ elist,
                                                float* __restrict__ out) {
    const int t = threadIdx.x;
    const int slot = t >> 5, lane = t & 31, h = lane >> 3;
    const int v = blockIdx.x * 8 + slot;           // grid is exactly 100000/8
    const int s = off_v[v], en = end_v[v];
    const int deg = en - s;

    __shared__ int   se[8][MAXDV];
    __shared__ float sa[8][MAXDV * HEADS];

    if (deg <= MAXDV && lane < deg) {
        int e = elist[s + lane];
        se[slot][lane] = e;
        *(float4*)&sa[slot][lane << 2] = *(const float4*)&alpha_le[e * HEADS];
    }
    const short4 resh = *(const short4*)&X0h[(size_t)v * CH + (lane << 2)];
    __syncthreads();

    float4 acc = make_float4(0.f, 0.f, 0.f, 0.f);
    if (deg <= MAXDV) {
        float mx = -INFINITY;
        for (int j = 0; j < deg; ++j) mx = fmaxf(mx, sa[slot][(j << 2) + h]);
        float ssum = 0.f;
        for (int j = 0; j < deg; ++j) ssum += __expf(sa[slot][(j << 2) + h] - mx);
        const float inv = 1.0f / (ssum + 1e-8f);
        for (int j = 0; j < deg; ++j) {
            float w = __expf(sa[slot][(j << 2) + h] - mx) * inv;
            short4 x = *(const short4*)&Xeh[(size_t)se[slot][j] * CH + (lane << 2)];
            acc.x += w * bf2f(x.x); acc.y += w * bf2f(x.y);
            acc.z += w * bf2f(x.z); acc.w += w * bf2f(x.w);
        }
    } else {
        // global-memory fallback (never taken for Poisson(6.4); correctness only)
        float mx = -INFINITY;
        for (int j = 0; j < deg; ++j) mx = fmaxf(mx, alpha_le[elist[s + j] * HEADS + h]);
        float ssum = 0.f;
        for (int j = 0; j < deg; ++j) ssum += __expf(alpha_le[elist[s + j] * HEADS + h] - mx);
        const float inv = 1.0f / (ssum + 1e-8f);
        for (int j = 0; j < deg; ++j) {
            int e = elist[s + j];
            float w = __expf(alpha_le[e * HEADS + h] - mx) * inv;
            short4 x = *(const short4*)&Xeh[(size_t)e * CH + (lane << 2)];
            acc.x += w * bf2f(x.x); acc.y += w * bf2f(x.y);
            acc.z += w * bf2f(x.z); acc.w += w * bf2f(x.w);
        }
    }
    float4 o = make_float4(acc.x + bf2f(resh.x), acc.y + bf2f(resh.y),
                           acc.z + bf2f(resh.z), acc.w + bf2f(resh.w));
    ((float4*)out)[(size_t)v * 32 + lane] = o;
}

extern "C" void kernel_launch(void* const* d_in, const int* in_sizes, int n_in,
                              void* d_out, int out_size, void* d_ws, size_t ws_size,
                              hipStream_t stream) {
    const float* X      = (const float*)d_in[0];
    const float* W      = (const float*)d_in[1];
    const float* att    = (const float*)d_in[2];
    const int*   vertex = (const int*)d_in[3];
    const int*   edges  = (const int*)d_in[4];
    float* out = (float*)d_out;

    char* ws = (char*)d_ws;
    short* X0h      = (short*)(ws + OFF_X0H);
    short* Xeh      = (short*)(ws + OFF_XEH);
    unsigned int* rank_pack = (unsigned int*)(ws + OFF_RANK);
    short* Wt       = (short*)(ws + OFF_WT);
    float* alpha_le = (float*)(ws + OFF_ALPHA);
    int* off_e   = (int*)(ws + OFF_OFFE);
    int* end_e   = (int*)(ws + OFF_ENDE);
    int* off_v   = (int*)(ws + OFF_OFFV);
    int* end_v   = (int*)(ws + OFF_ENDV);
    int* vlist_e = (int*)(ws + OFF_PIDXE);
    int* elist_v = (int*)(ws + OFF_PIDXV);
    int* cnt_e   = (int*)(ws + OFF_CNTE);
    int* cnt_v   = (int*)(ws + OFF_CNTV);
    int* totals  = (int*)(ws + OFF_TOT);

    hipMemsetAsync(ws + OFF_CNTE, 0, ZERO_BYTES, stream);

    k_wprep<<<64, 256, 0, stream>>>(W, Wt);
    k_gemm_rank<<<NG_GEMM + NR_RANK, 256, 0, stream>>>(X, Wt, X0h, vertex, edges,
                                                       cnt_e, cnt_v, rank_pack);
    k_offsets2<<<79 + 391, 256, 0, stream>>>(cnt_e, off_e, end_e, cnt_v, off_v, end_v, totals);
    k_scatter<<<N_PAIRS / 256, 256, 0, stream>>>(vertex, edges, rank_pack, off_e, off_v, vlist_e, elist_v);
    k_edge<<<N_EDGES / 8, 256, 0, stream>>>(X0h, off_e, end_e, vlist_e, att, Xeh, alpha_le);
    k_vertex<<<N_NODES / 8, 256, 0, stream>>>(X0h, Xeh, alpha_le, off_v, end_v, elist_v, out);
}